// Round 2
// baseline (800.497 us; speedup 1.0000x reference)
//
#include <hip/hip_runtime.h>
#include <hip/hip_bf16.h>
#include <hip/hip_cooperative_groups.h>

namespace cg = cooperative_groups;

// SAGEConv(mean), 3-dispatch pipeline (was 9):
//   D1 k_csr (coop, 1024 blk): hist + x->bf16 cast | sync | per-bucket scan
//        | sync | scatter (in-block bbase rebuild) | sync | counting sort
//   D2 k_gather_bf: 16-lanes/node CSR gather-mean (6250 blocks: TLP is king)
//   D3 k_tail (coop, 391 blk): MFMA+L2norm+ReLU+BN partials | sync |
//        redundant pstats reduce (L2) + BN-fold + FC out
// Legacy 9-dispatch path kept as fallback if cooperative occupancy fails.
// N=100000, E=1200000, F=H=64, C=16.
//
// Lessons: R4/R5/R7/R8 — device-scope atomics run at the shared coherence
// point; only LDS atomics are cheap. R10 — never shrink the random gather's
// grid. R11 — never serialize a scan into one block to save a launch.
// R12 — uint4/8-lane gather regressed (+11us): per-CU resident TLP was
// identical (both saturate 8 blk/CU); wider per-lane state bought nothing.
// R13 (this round): no kernel exceeds 44us (rocprof top-5 = fills only) yet
// wall is 212us -> ~half is dispatch-boundary overhead; merge via grid sync.

typedef __attribute__((ext_vector_type(8))) short short8;   // 8 bf16
typedef __attribute__((ext_vector_type(4))) float f32x4;

__device__ __forceinline__ unsigned short f2bf(float f) {
    unsigned int u = __builtin_bit_cast(unsigned int, f);
    u += 0x7FFFu + ((u >> 16) & 1u);
    return (unsigned short)(u >> 16);
}
__device__ __forceinline__ float bf2f(unsigned short s) {
    return __builtin_bit_cast(float, ((unsigned int)s) << 16);
}

#define CHUNK 8192

// 256-thread exclusive scan; all 256 threads of the block must call.
__device__ __forceinline__ int exclScan256(int v, int* swv) {
    const int t = threadIdx.x, lane = t & 63, wid = t >> 6;
    __syncthreads();                       // protect swv from prior use
    int s = v;
#pragma unroll
    for (int off = 1; off < 64; off <<= 1) {
        int tt = __shfl_up(s, off);
        if (lane >= off) s += tt;
    }
    if (lane == 63) swv[wid] = s;
    __syncthreads();
    if (t == 0) {
        int a = 0;
#pragma unroll
        for (int w = 0; w < 4; ++w) { int tt = swv[w]; swv[w] = a; a += tt; }
    }
    __syncthreads();
    return s - v + swv[wid];
}

// =====================  D1: cooperative CSR build  =====================
__global__ __launch_bounds__(256) void k_csr(
        const int* __restrict__ eidx, int* __restrict__ cnt,
        int* __restrict__ btot,
        const float4* __restrict__ x4, ushort4* __restrict__ xbf,
        unsigned int* __restrict__ ebuf,
        int* __restrict__ rowptr, int* __restrict__ colv,
        int E, int N, int NB, int NBLK, int n4, int do_x) {
    cg::grid_group grid = cg::this_grid();
    __shared__ int sh[512];
    __shared__ int sb[257];
    __shared__ int swv[4];
    const int tid = threadIdx.x;
    const int bid = blockIdx.x;
    const int GD = gridDim.x;

    // ---- phase 0: blocks [0,NBLK) bucket hist; blocks [NBLK,GD) bf16 cast
    if (bid < NBLK) {
        sh[tid] = 0;
        __syncthreads();
        const int base = bid * CHUNK;
        for (int i = tid; i < CHUNK; i += 256) {
            int e = base + i;
            if (e < E) atomicAdd(&sh[eidx[E + e] >> 9], 1);
        }
        __syncthreads();
        if (tid < NB) cnt[(size_t)tid * NBLK + bid] = sh[tid];
    } else if (do_x) {
        const int ncast = GD - NBLK;
        for (int i = (bid - NBLK) * 256 + tid; i < n4; i += ncast * 256) {
            float4 v = x4[i];
            xbf[i] = make_ushort4(f2bf(v.x), f2bf(v.y), f2bf(v.z), f2bf(v.w));
        }
    }
    __threadfence();
    grid.sync();

    // ---- phase 1: per-bucket coalesced scan over chunk row (blocks < NB)
    if (bid < NB) {
        int v = (tid < NBLK) ? cnt[(size_t)bid * NBLK + tid] : 0;
        int excl = exclScan256(v, swv);
        if (tid < NBLK) cnt[(size_t)bid * NBLK + tid] = excl;  // rel offset
        if (tid == 255) btot[bid] = excl + v;                  // bucket total
    }
    __threadfence();
    grid.sync();

    // ---- phase 2: scatter into bucket segments; bbase rebuilt in-block
    if (bid < NBLK) {
        int bv = (tid < NB) ? btot[tid] : 0;
        int bexcl = exclScan256(bv, swv);
        sh[tid] = (tid < NB) ? (bexcl + cnt[(size_t)tid * NBLK + bid]) : 0;
        __syncthreads();
        const int base = bid * CHUNK;
        for (int i = tid; i < CHUNK; i += 256) {
            int e = base + i;
            if (e < E) {
                int d = eidx[E + e];
                int s = eidx[e];
                int p = atomicAdd(&sh[d >> 9], 1);
                ebuf[p] = (unsigned int)s | ((unsigned int)(d & 511) << 17);
            }
        }
    }
    __threadfence();
    grid.sync();

    // ---- phase 3: per-bucket LDS counting sort -> rowptr + colv
    if (bid < NB) {
        int bv = (tid < NB) ? btot[tid] : 0;
        int bexcl = exclScan256(bv, swv);
        sb[tid] = bexcl;
        __syncthreads();
        const int segb = sb[bid];
        const int sege = segb + btot[bid];
        sh[2 * tid] = 0;
        sh[2 * tid + 1] = 0;
        __syncthreads();
        for (int i = segb + tid; i < sege; i += 256)
            atomicAdd(&sh[ebuf[i] >> 17], 1);
        __syncthreads();
        int a0 = sh[2 * tid], a1 = sh[2 * tid + 1];
        int ts = a0 + a1;
        const int lane = tid & 63, wid = tid >> 6;
        int s = ts;
#pragma unroll
        for (int off = 1; off < 64; off <<= 1) {
            int tt = __shfl_up(s, off);
            if (lane >= off) s += tt;
        }
        if (lane == 63) swv[wid] = s;
        __syncthreads();
        if (tid == 0) {
            int a = 0;
#pragma unroll
            for (int w = 0; w < 4; ++w) { int tt = swv[w]; swv[w] = a; a += tt; }
        }
        __syncthreads();
        int excl = s - ts + swv[wid];
        sh[2 * tid] = excl;
        sh[2 * tid + 1] = excl + a0;
        int node = bid * 512 + 2 * tid;
        if (node < N) rowptr[node] = segb + excl;
        if (node + 1 < N) rowptr[node + 1] = segb + excl + a0;
        __syncthreads();
        for (int i = segb + tid; i < sege; i += 256) {
            unsigned int u = ebuf[i];
            int p = atomicAdd(&sh[u >> 17], 1);
            colv[segb + p] = (int)(u & 0x1FFFFu);
        }
        if (bid == 0 && tid == 0) rowptr[N] = E;
    }
}

// ========== legacy (fallback) CSR kernels — proven 9-dispatch path ==========
__global__ __launch_bounds__(256) void k_prep(const int* __restrict__ eidx,
                                              int* __restrict__ cnt,
                                              const float4* __restrict__ x4,
                                              ushort4* __restrict__ xbf,
                                              int E, int NB, int NBLK,
                                              int n4, int do_x) {
    __shared__ int lh[256];
    const int tid = threadIdx.x;
    if ((int)blockIdx.x < NBLK) {
        lh[tid] = 0;
        __syncthreads();
        const int base = blockIdx.x * CHUNK;
        for (int i = tid; i < CHUNK; i += 256) {
            int e = base + i;
            if (e < E) atomicAdd(&lh[eidx[E + e] >> 9], 1);
        }
        __syncthreads();
        if (tid < NB) cnt[(size_t)tid * NBLK + blockIdx.x] = lh[tid];
    } else if (do_x) {
        int t = ((int)blockIdx.x - NBLK) * 256 + tid;
        if (t < n4) {
            float4 v = x4[t];
            xbf[t] = make_ushort4(f2bf(v.x), f2bf(v.y), f2bf(v.z), f2bf(v.w));
        }
    }
}

__global__ __launch_bounds__(256) void k_scanbkt(int* __restrict__ cnt,
                                                 int* __restrict__ btot,
                                                 int NBLK) {
    __shared__ int swv[4];
    const int b = blockIdx.x;
    const int t = threadIdx.x;
    int v = (t < NBLK) ? cnt[(size_t)b * NBLK + t] : 0;
    int excl = exclScan256(v, swv);
    if (t < NBLK) cnt[(size_t)b * NBLK + t] = excl;
    if (t == 255) btot[b] = excl + v;
}

__global__ __launch_bounds__(256) void k_bscanB(const int* __restrict__ btot,
                                                int* __restrict__ bbase,
                                                int* __restrict__ rowptr,
                                                int NB, int N, int E) {
    __shared__ int swv[4];
    const int t = threadIdx.x;
    int v = (t < NB) ? btot[t] : 0;
    int excl = exclScan256(v, swv);
    if (t < NB) bbase[t] = excl;
    if (t == 0) { bbase[NB] = E; rowptr[N] = E; }
}

__global__ __launch_bounds__(256) void k_bscatter(const int* __restrict__ eidx,
                                                  const int* __restrict__ cnt,
                                                  const int* __restrict__ bbase,
                                                  unsigned int* __restrict__ ebuf,
                                                  int E, int NB, int NBLK) {
    __shared__ int cur[256];
    const int tid = threadIdx.x;
    if (tid < NB)
        cur[tid] = bbase[tid] + cnt[(size_t)tid * NBLK + blockIdx.x];
    __syncthreads();
    const int base = blockIdx.x * CHUNK;
    for (int i = tid; i < CHUNK; i += 256) {
        int e = base + i;
        if (e < E) {
            int d = eidx[E + e];
            int s = eidx[e];
            int p = atomicAdd(&cur[d >> 9], 1);
            ebuf[p] = (unsigned int)s | ((unsigned int)(d & 511) << 17);
        }
    }
}

__global__ __launch_bounds__(256) void k_bfinal(const unsigned int* __restrict__ ebuf,
                                                const int* __restrict__ bbase,
                                                int* __restrict__ rowptr,
                                                int* __restrict__ colv, int N) {
    __shared__ int h[512];
    __shared__ int swv[4];
    const int b = blockIdx.x;
    const int tid = threadIdx.x;
    h[2 * tid] = 0;
    h[2 * tid + 1] = 0;
    __syncthreads();
    const int segb = bbase[b], sege = bbase[b + 1];
    for (int i = segb + tid; i < sege; i += 256)
        atomicAdd(&h[ebuf[i] >> 17], 1);
    __syncthreads();
    int a0 = h[2 * tid], a1 = h[2 * tid + 1];
    int ts = a0 + a1;
    const int lane = tid & 63, wid = tid >> 6;
    int s = ts;
#pragma unroll
    for (int off = 1; off < 64; off <<= 1) {
        int tt = __shfl_up(s, off);
        if (lane >= off) s += tt;
    }
    if (lane == 63) swv[wid] = s;
    __syncthreads();
    if (tid == 0) {
        int a = 0;
#pragma unroll
        for (int w = 0; w < 4; ++w) { int tt = swv[w]; swv[w] = a; a += tt; }
    }
    __syncthreads();
    int excl = s - ts + swv[wid];
    h[2 * tid] = excl;
    h[2 * tid + 1] = excl + a0;
    int node = b * 512 + 2 * tid;
    if (node < N) rowptr[node] = segb + excl;
    if (node + 1 < N) rowptr[node + 1] = segb + excl + a0;
    __syncthreads();
    for (int i = segb + tid; i < sege; i += 256) {
        unsigned int u = ebuf[i];
        int p = atomicAdd(&h[u >> 17], 1);
        colv[segb + p] = (int)(u & 0x1FFFFu);
    }
}

// ============ D2: gather-mean (bf16 x): 16 lanes/node, uint2 loads ============
__global__ __launch_bounds__(256) void k_gather_bf(
        const uint2* __restrict__ xbf2, const int* __restrict__ rowptr,
        const int* __restrict__ colv, uint2* __restrict__ mh2, int N) {
    int t = blockIdx.x * 256 + threadIdx.x;
    int n = t >> 4;
    int l = t & 15;
    if (n >= N) return;
    int b = rowptr[n], e = rowptr[n + 1];
    float a0 = 0.f, a1 = 0.f, a2 = 0.f, a3 = 0.f;
    int p = b;
    for (; p + 4 <= e; p += 4) {
        int s0 = colv[p], s1 = colv[p + 1], s2 = colv[p + 2], s3 = colv[p + 3];
        uint2 v0 = xbf2[(size_t)s0 * 16 + l];
        uint2 v1 = xbf2[(size_t)s1 * 16 + l];
        uint2 v2 = xbf2[(size_t)s2 * 16 + l];
        uint2 v3 = xbf2[(size_t)s3 * 16 + l];
        a0 += bf2f((unsigned short)(v0.x & 0xFFFF)) + bf2f((unsigned short)(v1.x & 0xFFFF)) +
              bf2f((unsigned short)(v2.x & 0xFFFF)) + bf2f((unsigned short)(v3.x & 0xFFFF));
        a1 += bf2f((unsigned short)(v0.x >> 16)) + bf2f((unsigned short)(v1.x >> 16)) +
              bf2f((unsigned short)(v2.x >> 16)) + bf2f((unsigned short)(v3.x >> 16));
        a2 += bf2f((unsigned short)(v0.y & 0xFFFF)) + bf2f((unsigned short)(v1.y & 0xFFFF)) +
              bf2f((unsigned short)(v2.y & 0xFFFF)) + bf2f((unsigned short)(v3.y & 0xFFFF));
        a3 += bf2f((unsigned short)(v0.y >> 16)) + bf2f((unsigned short)(v1.y >> 16)) +
              bf2f((unsigned short)(v2.y >> 16)) + bf2f((unsigned short)(v3.y >> 16));
    }
    for (; p < e; ++p) {
        int s0 = colv[p];
        uint2 v0 = xbf2[(size_t)s0 * 16 + l];
        a0 += bf2f((unsigned short)(v0.x & 0xFFFF));
        a1 += bf2f((unsigned short)(v0.x >> 16));
        a2 += bf2f((unsigned short)(v0.y & 0xFFFF));
        a3 += bf2f((unsigned short)(v0.y >> 16));
    }
    float inv = 1.0f / fmaxf((float)(e - b), 1.0f);
    uint2 o;
    o.x = (unsigned int)f2bf(a0 * inv) | ((unsigned int)f2bf(a1 * inv) << 16);
    o.y = (unsigned int)f2bf(a2 * inv) | ((unsigned int)f2bf(a3 * inv) << 16);
    mh2[(size_t)n * 16 + l] = o;
}

__global__ __launch_bounds__(256) void k_gather_f32(
        const float4* __restrict__ x4, const int* __restrict__ rowptr,
        const int* __restrict__ colv, ushort4* __restrict__ mh, int N) {
    int t = blockIdx.x * 256 + threadIdx.x;
    int n = t >> 4;
    int l = t & 15;
    if (n >= N) return;
    int b = rowptr[n], e = rowptr[n + 1];
    float ax = 0.f, ay = 0.f, az = 0.f, aw = 0.f;
    int p = b;
    for (; p + 4 <= e; p += 4) {
        int s0 = colv[p], s1 = colv[p + 1], s2 = colv[p + 2], s3 = colv[p + 3];
        float4 v0 = x4[(size_t)s0 * 16 + l];
        float4 v1 = x4[(size_t)s1 * 16 + l];
        float4 v2 = x4[(size_t)s2 * 16 + l];
        float4 v3 = x4[(size_t)s3 * 16 + l];
        ax += (v0.x + v1.x) + (v2.x + v3.x);
        ay += (v0.y + v1.y) + (v2.y + v3.y);
        az += (v0.z + v1.z) + (v2.z + v3.z);
        aw += (v0.w + v1.w) + (v2.w + v3.w);
    }
    for (; p < e; ++p) {
        int s0 = colv[p];
        float4 v0 = x4[(size_t)s0 * 16 + l];
        ax += v0.x; ay += v0.y; az += v0.z; aw += v0.w;
    }
    float inv = 1.0f / fmaxf((float)(e - b), 1.0f);
    mh[(size_t)n * 16 + l] = make_ushort4(f2bf(ax * inv), f2bf(ay * inv),
                                          f2bf(az * inv), f2bf(aw * inv));
}

// ===== fused body: MFMA [mean|x]@[Wl;Wr]^T + bl, L2norm, ReLU, BN partials ====
__device__ __forceinline__ void fused_body(
        const float* __restrict__ x,
        const unsigned short* __restrict__ xbf, int use_bf,
        const float* __restrict__ Wl, const float* __restrict__ bl,
        const float* __restrict__ Wr,
        unsigned short* __restrict__ mh, float* __restrict__ pstats,
        int N, float (*sRed)[128]) {
    const int tid = threadIdx.x;
    const int wid = tid >> 6;
    const int lane = tid & 63;
    const int l15 = lane & 15;
    const int quad = lane >> 4;

    short8 bfrag[4][4];
#pragma unroll
    for (int c = 0; c < 4; ++c) {
#pragma unroll
        for (int f = 0; f < 4; ++f) {
            const int n = f * 16 + l15;
            const float* wsrc = (c < 2)
                ? (Wl + (size_t)n * 64 + c * 32 + quad * 8)
                : (Wr + (size_t)n * 64 + (c - 2) * 32 + quad * 8);
            float4 w0 = *(const float4*)wsrc;
            float4 w1 = *(const float4*)(wsrc + 4);
            union { short8 v; unsigned short u[8]; } pk;
            pk.u[0] = f2bf(w0.x); pk.u[1] = f2bf(w0.y);
            pk.u[2] = f2bf(w0.z); pk.u[3] = f2bf(w0.w);
            pk.u[4] = f2bf(w1.x); pk.u[5] = f2bf(w1.y);
            pk.u[6] = f2bf(w1.z); pk.u[7] = f2bf(w1.w);
            bfrag[c][f] = pk.v;
        }
    }

    float blv[4];
#pragma unroll
    for (int f = 0; f < 4; ++f) blv[f] = bl[f * 16 + l15];

    float psum[4] = {0.f, 0.f, 0.f, 0.f};
    float psq[4] = {0.f, 0.f, 0.f, 0.f};

    for (int t4 = 0; t4 < 4; ++t4) {
        const int tbase = blockIdx.x * 256 + wid * 64 + t4 * 16;
        const int mrow = tbase + l15;
        const int mld = (mrow < N) ? mrow : (N - 1);
        f32x4 acc[4] = {{0.f, 0.f, 0.f, 0.f}, {0.f, 0.f, 0.f, 0.f},
                        {0.f, 0.f, 0.f, 0.f}, {0.f, 0.f, 0.f, 0.f}};
#pragma unroll
        for (int c = 0; c < 2; ++c) {
            short8 a = *(const short8*)(mh + (size_t)mld * 64 + c * 32 + quad * 8);
#pragma unroll
            for (int f = 0; f < 4; ++f)
                acc[f] = __builtin_amdgcn_mfma_f32_16x16x32_bf16(a, bfrag[c][f], acc[f], 0, 0, 0);
        }
        if (use_bf) {
#pragma unroll
            for (int c = 0; c < 2; ++c) {
                short8 a = *(const short8*)(xbf + (size_t)mld * 64 + c * 32 + quad * 8);
#pragma unroll
                for (int f = 0; f < 4; ++f)
                    acc[f] = __builtin_amdgcn_mfma_f32_16x16x32_bf16(a, bfrag[c + 2][f], acc[f], 0, 0, 0);
            }
        } else {
#pragma unroll
            for (int c = 0; c < 2; ++c) {
                const float* xp = x + (size_t)mld * 64 + c * 32 + quad * 8;
                float4 a0 = *(const float4*)xp;
                float4 a1 = *(const float4*)(xp + 4);
                union { short8 v; unsigned short u[8]; } pk;
                pk.u[0] = f2bf(a0.x); pk.u[1] = f2bf(a0.y);
                pk.u[2] = f2bf(a0.z); pk.u[3] = f2bf(a0.w);
                pk.u[4] = f2bf(a1.x); pk.u[5] = f2bf(a1.y);
                pk.u[6] = f2bf(a1.z); pk.u[7] = f2bf(a1.w);
#pragma unroll
                for (int f = 0; f < 4; ++f)
                    acc[f] = __builtin_amdgcn_mfma_f32_16x16x32_bf16(pk.v, bfrag[c + 2][f], acc[f], 0, 0, 0);
            }
        }

#pragma unroll
        for (int reg = 0; reg < 4; ++reg) {
            const int node = tbase + quad * 4 + reg;
            float hv[4];
            float ss = 0.f;
#pragma unroll
            for (int f = 0; f < 4; ++f) {
                hv[f] = acc[f][reg] + blv[f];
                ss += hv[f] * hv[f];
            }
            ss += __shfl_xor(ss, 1);
            ss += __shfl_xor(ss, 2);
            ss += __shfl_xor(ss, 4);
            ss += __shfl_xor(ss, 8);
            float sc = 1.0f / fmaxf(sqrtf(ss), 1e-12f);
            if (node < N) {
#pragma unroll
                for (int f = 0; f < 4; ++f) {
                    float r = fmaxf(hv[f] * sc, 0.f);
                    unsigned short rb = f2bf(r);
                    float e = bf2f(rb);
                    mh[(size_t)node * 64 + f * 16 + l15] = rb;
                    psum[f] += e;
                    psq[f] += e * e;
                }
            }
        }
    }

#pragma unroll
    for (int f = 0; f < 4; ++f) {
        psum[f] += __shfl_xor(psum[f], 16);
        psum[f] += __shfl_xor(psum[f], 32);
        psq[f] += __shfl_xor(psq[f], 16);
        psq[f] += __shfl_xor(psq[f], 32);
    }
    if (lane < 16) {
#pragma unroll
        for (int f = 0; f < 4; ++f) {
            sRed[wid][f * 16 + l15] = psum[f];
            sRed[wid][64 + f * 16 + l15] = psq[f];
        }
    }
    __syncthreads();
    if (tid < 128) {
        float v = sRed[0][tid] + sRed[1][tid] + sRed[2][tid] + sRed[3][tid];
        pstats[(size_t)blockIdx.x * 128 + tid] = v;
    }
}

// ================= D3: cooperative fused + stats + out =================
__global__ __launch_bounds__(256) void k_tail(
        const float* __restrict__ x,
        const unsigned short* __restrict__ xbf, int use_bf,
        const float* __restrict__ Wl, const float* __restrict__ bl,
        const float* __restrict__ Wr,
        unsigned short* __restrict__ mh, float* __restrict__ pstats,
        const float* __restrict__ gamma, const float* __restrict__ beta,
        const float* __restrict__ Wfc, const float* __restrict__ bfc,
        float* __restrict__ out, int N, int fb2) {
    cg::grid_group grid = cg::this_grid();
    __shared__ float sRed[4][128];
    __shared__ float sP[256];
    __shared__ float sStats[128];
    __shared__ float sWm[64 * 16];
    __shared__ float sShift[64];
    __shared__ float sBase[16];
    const int tid = threadIdx.x;
    const int bid = blockIdx.x;

    // phase A: MFMA + L2norm + ReLU + BN partials
    fused_body(x, xbf, use_bf, Wl, bl, Wr, mh, pstats, N, sRed);
    __threadfence();
    grid.sync();

    // phase B: every block redundantly reduces pstats (L2-resident, ~2us agg)
    {
        const int col = tid & 127, half = tid >> 7;
        float s = 0.f;
        for (int r = half; r < fb2; r += 2) s += pstats[(size_t)r * 128 + col];
        sP[tid] = s;
        __syncthreads();
        if (tid < 128) sStats[tid] = sP[tid] + sP[tid + 128];
        __syncthreads();
    }

    // phase C: BN-fold + FC for this block's 256 nodes
    const float invN = 1.0f / (float)N;
    if (tid < 64) {
        float mu = sStats[tid] * invN;
        float var = sStats[64 + tid] * invN - mu * mu;
        float sc = gamma[tid] / sqrtf(var + 1e-5f);
        sShift[tid] = beta[tid] - mu * sc;
#pragma unroll
        for (int c = 0; c < 16; ++c) sWm[tid * 16 + c] = Wfc[c * 64 + tid] * sc;
    }
    __syncthreads();
    if (tid < 16) {
        float b = bfc[tid];
#pragma unroll
        for (int j = 0; j < 64; ++j) b += sShift[j] * Wfc[tid * 64 + j];
        sBase[tid] = b;
    }
    __syncthreads();
#pragma unroll
    for (int it = 0; it < 16; ++it) {
        int g = it * 256 + tid;
        int nl = g >> 4;
        int c = g & 15;
        int n = bid * 256 + nl;
        if (n < N) {
            const ushort4* h4 = (const ushort4*)(mh + (size_t)n * 64);
            float acc = sBase[c];
#pragma unroll
            for (int jq = 0; jq < 16; ++jq) {
                ushort4 v = h4[jq];
                acc += bf2f(v.x) * sWm[(jq * 4 + 0) * 16 + c];
                acc += bf2f(v.y) * sWm[(jq * 4 + 1) * 16 + c];
                acc += bf2f(v.z) * sWm[(jq * 4 + 2) * 16 + c];
                acc += bf2f(v.w) * sWm[(jq * 4 + 3) * 16 + c];
            }
            out[(size_t)n * 16 + c] = acc;
        }
    }
}

// ===================== legacy fused / stats / out =====================
__global__ __launch_bounds__(256) void k_fused(
        const float* __restrict__ x,
        const unsigned short* __restrict__ xbf, int use_bf,
        const float* __restrict__ Wl, const float* __restrict__ bl,
        const float* __restrict__ Wr,
        unsigned short* __restrict__ mh, float* __restrict__ pstats, int N) {
    __shared__ float sRed[4][128];
    fused_body(x, xbf, use_bf, Wl, bl, Wr, mh, pstats, N, sRed);
}

__global__ __launch_bounds__(64) void k_stats(const float* __restrict__ pstats,
                                              float* __restrict__ stats, int nblk) {
    int col = blockIdx.x;
    int l = threadIdx.x;
    float s = 0.f;
    for (int r = l; r < nblk; r += 64) s += pstats[(size_t)r * 128 + col];
    s += __shfl_xor(s, 1);
    s += __shfl_xor(s, 2);
    s += __shfl_xor(s, 4);
    s += __shfl_xor(s, 8);
    s += __shfl_xor(s, 16);
    s += __shfl_xor(s, 32);
    if (l == 0) stats[col] = s;
}

__global__ __launch_bounds__(256) void k_out(
        const unsigned short* __restrict__ h, const float* __restrict__ stats,
        const float* __restrict__ gamma, const float* __restrict__ beta,
        const float* __restrict__ Wfc, const float* __restrict__ bfc,
        float* __restrict__ out, int N) {
    __shared__ float sWm[64 * 16];
    __shared__ float sShift[64];
    __shared__ float sBase[16];
    const int tid = threadIdx.x;
    const float invN = 1.0f / (float)N;
    if (tid < 64) {
        float mu = stats[tid] * invN;
        float var = stats[64 + tid] * invN - mu * mu;
        float sc = gamma[tid] / sqrtf(var + 1e-5f);
        sShift[tid] = beta[tid] - mu * sc;
#pragma unroll
        for (int c = 0; c < 16; ++c) sWm[tid * 16 + c] = Wfc[c * 64 + tid] * sc;
    }
    __syncthreads();
    if (tid < 16) {
        float b = bfc[tid];
#pragma unroll
        for (int j = 0; j < 64; ++j) b += sShift[j] * Wfc[tid * 64 + j];
        sBase[tid] = b;
    }
    __syncthreads();
    int g = blockIdx.x * 256 + tid;
    int n = g >> 4;
    int c = g & 15;
    if (n >= N) return;
    const ushort4* h4 = (const ushort4*)(h + (size_t)n * 64);
    float acc = sBase[c];
#pragma unroll
    for (int jq = 0; jq < 16; ++jq) {
        ushort4 v = h4[jq];
        acc += bf2f(v.x) * sWm[(jq * 4 + 0) * 16 + c];
        acc += bf2f(v.y) * sWm[(jq * 4 + 1) * 16 + c];
        acc += bf2f(v.z) * sWm[(jq * 4 + 2) * 16 + c];
        acc += bf2f(v.w) * sWm[(jq * 4 + 3) * 16 + c];
    }
    out[(size_t)n * 16 + c] = acc;
}

// ============================== host ==============================
extern "C" void kernel_launch(void* const* d_in, const int* in_sizes, int n_in,
                              void* d_out, int out_size, void* d_ws, size_t ws_size,
                              hipStream_t stream) {
    const int* eidx = (const int*)d_in[0];
    const float* x = (const float*)d_in[1];
    const float* Wl = (const float*)d_in[2];
    const float* bl = (const float*)d_in[3];
    const float* Wr = (const float*)d_in[4];
    const float* gamma = (const float*)d_in[5];
    const float* beta = (const float*)d_in[6];
    const float* Wfc = (const float*)d_in[7];
    const float* bfc = (const float*)d_in[8];
    float* out = (float*)d_out;

    const int E = in_sizes[0] / 2;
    const int N = in_sizes[1] / 64;
    const int NB = (N + 511) >> 9;
    const int NBLK = (E + CHUNK - 1) / CHUNK;
    const int fb2 = (N + 255) / 256;
    const int n4 = N * 16;

    // layout (4B words):
    int* cnt = (int*)d_ws;                                     // NB*NBLK
    int* btot = cnt + (size_t)NB * NBLK;                       // NB
    int* bbase = btot + NB;                                    // NB+1 (legacy)
    int* rowptr = bbase + NB + 1;                              // N+1
    float* pstats = (float*)(rowptr + N + 1);                  // fb2*128
    float* stats = pstats + (size_t)fb2 * 128;                 // 128
    int* colv = (int*)(stats + 128);                           // E
    unsigned int* ebuf = (unsigned int*)(colv + E);            // E
    unsigned short* mh = (unsigned short*)(((uintptr_t)(ebuf + E) + 15) & ~(uintptr_t)15);
    unsigned short* xbf = mh + (size_t)N * 64;                 // N*64 bf16 opt

    size_t need_bf = (size_t)((char*)(xbf + (size_t)N * 64) - (char*)d_ws);
    const int use_bf = (ws_size >= need_bf) ? 1 : 0;

    // one-time cooperative capability / occupancy probe (host-side queries only)
    static int g_init = 0;
    static int g_numCU = 0, g_coopDev = 0, g_mCsr = 0, g_mTail = 0;
    if (!g_init) {
        int dev = 0;
        hipGetDevice(&dev);
        hipDeviceProp_t prop{};
        hipGetDeviceProperties(&prop, dev);
        g_numCU = prop.multiProcessorCount;
        g_coopDev = prop.cooperativeLaunch;
        hipOccupancyMaxActiveBlocksPerMultiprocessor(&g_mCsr, reinterpret_cast<const void*>(k_csr), 256, 0);
        hipOccupancyMaxActiveBlocksPerMultiprocessor(&g_mTail, reinterpret_cast<const void*>(k_tail), 256, 0);
        g_init = 1;
    }

    const int maxNBx = (NB > NBLK) ? NB : NBLK;
    int gridCsr = g_mCsr * g_numCU;
    if (gridCsr > 1024) gridCsr = 1024;
    const bool coop_csr = g_coopDev && (gridCsr >= maxNBx + 64);
    const bool coop_tail = g_coopDev && (g_mTail * g_numCU >= fb2);

    // ---------------- D1: CSR build ----------------
    if (coop_csr) {
        const int* eidx_ = eidx;
        int* cnt_ = cnt; int* btot_ = btot;
        const float4* x4_ = (const float4*)x;
        ushort4* xbf4_ = (ushort4*)xbf;
        unsigned int* ebuf_ = ebuf;
        int* rowptr_ = rowptr; int* colv_ = colv;
        int E_ = E, N_ = N, NB_ = NB, NBLK_ = NBLK, n4_ = n4, ub_ = use_bf;
        void* args[] = {&eidx_, &cnt_, &btot_, &x4_, &xbf4_, &ebuf_,
                        &rowptr_, &colv_, &E_, &N_, &NB_, &NBLK_, &n4_, &ub_};
        hipLaunchCooperativeKernel(reinterpret_cast<const void*>(k_csr),
                                   dim3(gridCsr), dim3(256), args, 0, stream);
    } else {
        int cbl = use_bf ? (n4 + 255) / 256 : 0;
        k_prep<<<NBLK + cbl, 256, 0, stream>>>(eidx, cnt, (const float4*)x,
                                               (ushort4*)xbf, E, NB, NBLK, n4, use_bf);
        k_scanbkt<<<NB, 256, 0, stream>>>(cnt, btot, NBLK);
        k_bscanB<<<1, 256, 0, stream>>>(btot, bbase, rowptr, NB, N, E);
        k_bscatter<<<NBLK, 256, 0, stream>>>(eidx, cnt, bbase, ebuf, E, NB, NBLK);
        k_bfinal<<<NB, 256, 0, stream>>>(ebuf, bbase, rowptr, colv, N);
    }

    // ---------------- D2: gather-mean ----------------
    int gblocks = (int)(((size_t)N * 16 + 255) / 256);
    if (use_bf) {
        k_gather_bf<<<gblocks, 256, 0, stream>>>((const uint2*)xbf, rowptr, colv,
                                                 (uint2*)mh, N);
    } else {
        k_gather_f32<<<gblocks, 256, 0, stream>>>((const float4*)x, rowptr, colv,
                                                  (ushort4*)mh, N);
    }

    // ---------------- D3: fused + stats + out ----------------
    if (coop_tail) {
        const float* x_ = x;
        const unsigned short* xbf_ = xbf;
        int ub_ = use_bf;
        const float* Wl_ = Wl; const float* bl_ = bl; const float* Wr_ = Wr;
        unsigned short* mh_ = mh; float* pstats_ = pstats;
        const float* g_ = gamma; const float* b_ = beta;
        const float* Wfc_ = Wfc; const float* bfc_ = bfc;
        float* out_ = out;
        int N_ = N, fb2_ = fb2;
        void* args[] = {&x_, &xbf_, &ub_, &Wl_, &bl_, &Wr_, &mh_, &pstats_,
                        &g_, &b_, &Wfc_, &bfc_, &out_, &N_, &fb2_};
        hipLaunchCooperativeKernel(reinterpret_cast<const void*>(k_tail),
                                   dim3(fb2), dim3(256), args, 0, stream);
    } else {
        k_fused<<<fb2, 256, 0, stream>>>(x, xbf, use_bf, Wl, bl, Wr, mh, pstats, N);
        k_stats<<<128, 64, 0, stream>>>(pstats, stats, fb2);
        int oblocks = (int)(((size_t)N * 16 + 255) / 256);
        k_out<<<oblocks, 256, 0, stream>>>(mh, stats, gamma, beta, Wfc, bfc, out, N);
    }
}

// Round 3
// 269.704 us; speedup vs baseline: 2.9681x; 2.9681x over previous
//
#include <hip/hip_runtime.h>
#include <hip/hip_bf16.h>

// SAGEConv(mean), 7-dispatch pipeline, zero grid syncs:
//   k_prep    = bucket histogram (LDS atomics) + x->bf16 cast + zero done-ctr
//   k_scanbkt = per-bucket coalesced scan over chunks (rel offsets + btot)
//   k_bscatter= in-block bbase rebuild + scatter packed (dst&511)<<17|src
//   k_bfinal  = in-block bbase rebuild + per-bucket LDS counting sort
//   k_gather  = 16-lanes/node CSR gather-mean (6250 blocks: TLP is king)
//   k_fused   = MFMA [mean|x]@[Wl;Wr]^T + L2norm + ReLU + BN partials
//               + last-block-done pstats reduce (replaces k_stats)
//   k_out     = BN-fold + FC
// N=100000, E=1200000, F=H=64, C=16.
//
// Lessons: R4/R5/R7/R8 — device-scope atomics run at the shared coherence
// point; only LDS atomics are cheap. R10 — never shrink the random gather's
// grid. R11 — never serialize a scan into one block to save a launch.
// R12 — uint4/8-lane gather regressed: same per-CU TLP, wider state, no win.
// R13 — grid.sync() costs ~200us on MI355X (1024 blocks spinning on a
// device-scope atomic across 8 non-coherent XCD L2s; VALUBusy 0.46%).
// NEVER trade dispatch boundaries (~10us) for grid syncs (~200us).
// R14 (this round): cut boundaries WITHOUT sync — in-block bbase rebuild
// (kills 1-block k_bscanB) + last-block-done BN reduce (kills k_stats).

typedef __attribute__((ext_vector_type(8))) short short8;   // 8 bf16
typedef __attribute__((ext_vector_type(4))) float f32x4;

__device__ __forceinline__ unsigned short f2bf(float f) {
    unsigned int u = __builtin_bit_cast(unsigned int, f);
    u += 0x7FFFu + ((u >> 16) & 1u);
    return (unsigned short)(u >> 16);
}
__device__ __forceinline__ float bf2f(unsigned short s) {
    return __builtin_bit_cast(float, ((unsigned int)s) << 16);
}

#define CHUNK 8192

// 256-thread exclusive scan; all 256 threads of the block must call.
__device__ __forceinline__ int exclScan256(int v, int* swv) {
    const int t = threadIdx.x, lane = t & 63, wid = t >> 6;
    __syncthreads();                       // protect swv from prior use
    int s = v;
#pragma unroll
    for (int off = 1; off < 64; off <<= 1) {
        int tt = __shfl_up(s, off);
        if (lane >= off) s += tt;
    }
    if (lane == 63) swv[wid] = s;
    __syncthreads();
    if (t == 0) {
        int a = 0;
#pragma unroll
        for (int w = 0; w < 4; ++w) { int tt = swv[w]; swv[w] = a; a += tt; }
    }
    __syncthreads();
    return s - v + swv[wid];
}

// ---------------- k_prep: blocks [0,NBLK) = bucket hist; rest = x->bf16 cast
__global__ __launch_bounds__(256) void k_prep(const int* __restrict__ eidx,
                                              int* __restrict__ cnt,
                                              const float4* __restrict__ x4,
                                              ushort4* __restrict__ xbf,
                                              int* __restrict__ done,
                                              int E, int NB, int NBLK,
                                              int n4, int do_x) {
    __shared__ int lh[256];
    const int tid = threadIdx.x;
    if ((int)blockIdx.x < NBLK) {
        if (blockIdx.x == 0 && tid == 0) *done = 0;   // k_fused ticket counter
        lh[tid] = 0;
        __syncthreads();
        const int base = blockIdx.x * CHUNK;
        for (int i = tid; i < CHUNK; i += 256) {
            int e = base + i;
            if (e < E) atomicAdd(&lh[eidx[E + e] >> 9], 1);
        }
        __syncthreads();
        if (tid < NB) cnt[(size_t)tid * NBLK + blockIdx.x] = lh[tid];
    } else if (do_x) {
        int t = ((int)blockIdx.x - NBLK) * 256 + tid;
        if (t < n4) {
            float4 v = x4[t];
            xbf[t] = make_ushort4(f2bf(v.x), f2bf(v.y), f2bf(v.z), f2bf(v.w));
        }
    }
}

// -------- k_scanbkt: one block per bucket; coalesced scan over its chunk row
__global__ __launch_bounds__(256) void k_scanbkt(int* __restrict__ cnt,
                                                 int* __restrict__ btot,
                                                 int NBLK) {
    __shared__ int swv[4];
    const int b = blockIdx.x;
    const int t = threadIdx.x;
    int v = (t < NBLK) ? cnt[(size_t)b * NBLK + t] : 0;
    int excl = exclScan256(v, swv);
    if (t < NBLK) cnt[(size_t)b * NBLK + t] = excl;   // relative offset
    if (t == 255) btot[b] = excl + v;                 // bucket total
}

// ------ k_bscatter: in-block bbase rebuild (scan btot) + scatter to segments
__global__ __launch_bounds__(256) void k_bscatter(const int* __restrict__ eidx,
                                                  const int* __restrict__ cnt,
                                                  const int* __restrict__ btot,
                                                  unsigned int* __restrict__ ebuf,
                                                  int E, int NB, int NBLK) {
    __shared__ int cur[256];
    __shared__ int swv[4];
    const int tid = threadIdx.x;
    int bv = (tid < NB) ? btot[tid] : 0;
    int bexcl = exclScan256(bv, swv);
    if (tid < NB)
        cur[tid] = bexcl + cnt[(size_t)tid * NBLK + blockIdx.x];
    __syncthreads();
    const int base = blockIdx.x * CHUNK;
    for (int i = tid; i < CHUNK; i += 256) {
        int e = base + i;
        if (e < E) {
            int d = eidx[E + e];
            int s = eidx[e];
            int p = atomicAdd(&cur[d >> 9], 1);
            ebuf[p] = (unsigned int)s | ((unsigned int)(d & 511) << 17);
        }
    }
}

// ---- k_bfinal: in-block bbase rebuild + per-bucket LDS counting sort
__global__ __launch_bounds__(256) void k_bfinal(const unsigned int* __restrict__ ebuf,
                                                const int* __restrict__ btot,
                                                int* __restrict__ rowptr,
                                                int* __restrict__ colv,
                                                int N, int NB, int E) {
    __shared__ int h[512];
    __shared__ int swv[4];
    __shared__ int sseg[2];
    const int b = blockIdx.x;
    const int tid = threadIdx.x;
    int bv = (tid < NB) ? btot[tid] : 0;
    int bexcl = exclScan256(bv, swv);
    if (tid == b) { sseg[0] = bexcl; sseg[1] = bexcl + bv; }   // b < NB <= 256
    h[2 * tid] = 0;
    h[2 * tid + 1] = 0;
    __syncthreads();
    const int segb = sseg[0], sege = sseg[1];
    for (int i = segb + tid; i < sege; i += 256)
        atomicAdd(&h[ebuf[i] >> 17], 1);
    __syncthreads();
    int a0 = h[2 * tid], a1 = h[2 * tid + 1];
    int ts = a0 + a1;
    const int lane = tid & 63, wid = tid >> 6;
    int s = ts;
#pragma unroll
    for (int off = 1; off < 64; off <<= 1) {
        int tt = __shfl_up(s, off);
        if (lane >= off) s += tt;
    }
    if (lane == 63) swv[wid] = s;
    __syncthreads();
    if (tid == 0) {
        int a = 0;
#pragma unroll
        for (int w = 0; w < 4; ++w) { int tt = swv[w]; swv[w] = a; a += tt; }
    }
    __syncthreads();
    int excl = s - ts + swv[wid];
    h[2 * tid] = excl;
    h[2 * tid + 1] = excl + a0;
    int node = b * 512 + 2 * tid;
    if (node < N) rowptr[node] = segb + excl;
    if (node + 1 < N) rowptr[node + 1] = segb + excl + a0;
    __syncthreads();
    for (int i = segb + tid; i < sege; i += 256) {
        unsigned int u = ebuf[i];
        int p = atomicAdd(&h[u >> 17], 1);
        colv[segb + p] = (int)(u & 0x1FFFFu);
    }
    if (b == 0 && tid == 0) rowptr[N] = E;
}

// ============ gather-mean (bf16 x): 16 lanes/node, uint2 loads ============
__global__ __launch_bounds__(256) void k_gather_bf(
        const uint2* __restrict__ xbf2, const int* __restrict__ rowptr,
        const int* __restrict__ colv, uint2* __restrict__ mh2, int N) {
    int t = blockIdx.x * 256 + threadIdx.x;
    int n = t >> 4;
    int l = t & 15;
    if (n >= N) return;
    int b = rowptr[n], e = rowptr[n + 1];
    float a0 = 0.f, a1 = 0.f, a2 = 0.f, a3 = 0.f;
    int p = b;
    for (; p + 4 <= e; p += 4) {
        int s0 = colv[p], s1 = colv[p + 1], s2 = colv[p + 2], s3 = colv[p + 3];
        uint2 v0 = xbf2[(size_t)s0 * 16 + l];
        uint2 v1 = xbf2[(size_t)s1 * 16 + l];
        uint2 v2 = xbf2[(size_t)s2 * 16 + l];
        uint2 v3 = xbf2[(size_t)s3 * 16 + l];
        a0 += bf2f((unsigned short)(v0.x & 0xFFFF)) + bf2f((unsigned short)(v1.x & 0xFFFF)) +
              bf2f((unsigned short)(v2.x & 0xFFFF)) + bf2f((unsigned short)(v3.x & 0xFFFF));
        a1 += bf2f((unsigned short)(v0.x >> 16)) + bf2f((unsigned short)(v1.x >> 16)) +
              bf2f((unsigned short)(v2.x >> 16)) + bf2f((unsigned short)(v3.x >> 16));
        a2 += bf2f((unsigned short)(v0.y & 0xFFFF)) + bf2f((unsigned short)(v1.y & 0xFFFF)) +
              bf2f((unsigned short)(v2.y & 0xFFFF)) + bf2f((unsigned short)(v3.y & 0xFFFF));
        a3 += bf2f((unsigned short)(v0.y >> 16)) + bf2f((unsigned short)(v1.y >> 16)) +
              bf2f((unsigned short)(v2.y >> 16)) + bf2f((unsigned short)(v3.y >> 16));
    }
    for (; p < e; ++p) {
        int s0 = colv[p];
        uint2 v0 = xbf2[(size_t)s0 * 16 + l];
        a0 += bf2f((unsigned short)(v0.x & 0xFFFF));
        a1 += bf2f((unsigned short)(v0.x >> 16));
        a2 += bf2f((unsigned short)(v0.y & 0xFFFF));
        a3 += bf2f((unsigned short)(v0.y >> 16));
    }
    float inv = 1.0f / fmaxf((float)(e - b), 1.0f);
    uint2 o;
    o.x = (unsigned int)f2bf(a0 * inv) | ((unsigned int)f2bf(a1 * inv) << 16);
    o.y = (unsigned int)f2bf(a2 * inv) | ((unsigned int)f2bf(a3 * inv) << 16);
    mh2[(size_t)n * 16 + l] = o;
}

__global__ __launch_bounds__(256) void k_gather_f32(
        const float4* __restrict__ x4, const int* __restrict__ rowptr,
        const int* __restrict__ colv, ushort4* __restrict__ mh, int N) {
    int t = blockIdx.x * 256 + threadIdx.x;
    int n = t >> 4;
    int l = t & 15;
    if (n >= N) return;
    int b = rowptr[n], e = rowptr[n + 1];
    float ax = 0.f, ay = 0.f, az = 0.f, aw = 0.f;
    int p = b;
    for (; p + 4 <= e; p += 4) {
        int s0 = colv[p], s1 = colv[p + 1], s2 = colv[p + 2], s3 = colv[p + 3];
        float4 v0 = x4[(size_t)s0 * 16 + l];
        float4 v1 = x4[(size_t)s1 * 16 + l];
        float4 v2 = x4[(size_t)s2 * 16 + l];
        float4 v3 = x4[(size_t)s3 * 16 + l];
        ax += (v0.x + v1.x) + (v2.x + v3.x);
        ay += (v0.y + v1.y) + (v2.y + v3.y);
        az += (v0.z + v1.z) + (v2.z + v3.z);
        aw += (v0.w + v1.w) + (v2.w + v3.w);
    }
    for (; p < e; ++p) {
        int s0 = colv[p];
        float4 v0 = x4[(size_t)s0 * 16 + l];
        ax += v0.x; ay += v0.y; az += v0.z; aw += v0.w;
    }
    float inv = 1.0f / fmaxf((float)(e - b), 1.0f);
    mh[(size_t)n * 16 + l] = make_ushort4(f2bf(ax * inv), f2bf(ay * inv),
                                          f2bf(az * inv), f2bf(aw * inv));
}

// --------- k_fused: MFMA [mean|x]@[Wl;Wr]^T + bl, L2norm, ReLU, BN partials,
// then last-arriving block reduces pstats -> stats (replaces k_stats).
__global__ __launch_bounds__(256) void k_fused(
        const float* __restrict__ x,
        const unsigned short* __restrict__ xbf, int use_bf,
        const float* __restrict__ Wl, const float* __restrict__ bl,
        const float* __restrict__ Wr,
        unsigned short* __restrict__ mh,   // in: bf16 mean; out: bf16 h
        float* __restrict__ pstats, float* __restrict__ stats,
        int* __restrict__ done, int fb2, int N) {
    __shared__ float sRed[4][128];
    __shared__ float sP[256];
    __shared__ int isLast;

    const int tid = threadIdx.x;
    const int wid = tid >> 6;
    const int lane = tid & 63;
    const int l15 = lane & 15;
    const int quad = lane >> 4;

    short8 bfrag[4][4];
#pragma unroll
    for (int c = 0; c < 4; ++c) {
#pragma unroll
        for (int f = 0; f < 4; ++f) {
            const int n = f * 16 + l15;
            const float* wsrc = (c < 2)
                ? (Wl + (size_t)n * 64 + c * 32 + quad * 8)
                : (Wr + (size_t)n * 64 + (c - 2) * 32 + quad * 8);
            float4 w0 = *(const float4*)wsrc;
            float4 w1 = *(const float4*)(wsrc + 4);
            union { short8 v; unsigned short u[8]; } pk;
            pk.u[0] = f2bf(w0.x); pk.u[1] = f2bf(w0.y);
            pk.u[2] = f2bf(w0.z); pk.u[3] = f2bf(w0.w);
            pk.u[4] = f2bf(w1.x); pk.u[5] = f2bf(w1.y);
            pk.u[6] = f2bf(w1.z); pk.u[7] = f2bf(w1.w);
            bfrag[c][f] = pk.v;
        }
    }

    float blv[4];
#pragma unroll
    for (int f = 0; f < 4; ++f) blv[f] = bl[f * 16 + l15];

    float psum[4] = {0.f, 0.f, 0.f, 0.f};
    float psq[4] = {0.f, 0.f, 0.f, 0.f};

    for (int t4 = 0; t4 < 4; ++t4) {
        const int tbase = blockIdx.x * 256 + wid * 64 + t4 * 16;
        const int mrow = tbase + l15;
        const int mld = (mrow < N) ? mrow : (N - 1);
        f32x4 acc[4] = {{0.f, 0.f, 0.f, 0.f}, {0.f, 0.f, 0.f, 0.f},
                        {0.f, 0.f, 0.f, 0.f}, {0.f, 0.f, 0.f, 0.f}};
#pragma unroll
        for (int c = 0; c < 2; ++c) {
            short8 a = *(const short8*)(mh + (size_t)mld * 64 + c * 32 + quad * 8);
#pragma unroll
            for (int f = 0; f < 4; ++f)
                acc[f] = __builtin_amdgcn_mfma_f32_16x16x32_bf16(a, bfrag[c][f], acc[f], 0, 0, 0);
        }
        if (use_bf) {
#pragma unroll
            for (int c = 0; c < 2; ++c) {
                short8 a = *(const short8*)(xbf + (size_t)mld * 64 + c * 32 + quad * 8);
#pragma unroll
                for (int f = 0; f < 4; ++f)
                    acc[f] = __builtin_amdgcn_mfma_f32_16x16x32_bf16(a, bfrag[c + 2][f], acc[f], 0, 0, 0);
            }
        } else {
#pragma unroll
            for (int c = 0; c < 2; ++c) {
                const float* xp = x + (size_t)mld * 64 + c * 32 + quad * 8;
                float4 a0 = *(const float4*)xp;
                float4 a1 = *(const float4*)(xp + 4);
                union { short8 v; unsigned short u[8]; } pk;
                pk.u[0] = f2bf(a0.x); pk.u[1] = f2bf(a0.y);
                pk.u[2] = f2bf(a0.z); pk.u[3] = f2bf(a0.w);
                pk.u[4] = f2bf(a1.x); pk.u[5] = f2bf(a1.y);
                pk.u[6] = f2bf(a1.z); pk.u[7] = f2bf(a1.w);
#pragma unroll
                for (int f = 0; f < 4; ++f)
                    acc[f] = __builtin_amdgcn_mfma_f32_16x16x32_bf16(pk.v, bfrag[c + 2][f], acc[f], 0, 0, 0);
            }
        }

#pragma unroll
        for (int reg = 0; reg < 4; ++reg) {
            const int node = tbase + quad * 4 + reg;
            float hv[4];
            float ss = 0.f;
#pragma unroll
            for (int f = 0; f < 4; ++f) {
                hv[f] = acc[f][reg] + blv[f];
                ss += hv[f] * hv[f];
            }
            ss += __shfl_xor(ss, 1);
            ss += __shfl_xor(ss, 2);
            ss += __shfl_xor(ss, 4);
            ss += __shfl_xor(ss, 8);
            float sc = 1.0f / fmaxf(sqrtf(ss), 1e-12f);
            if (node < N) {
#pragma unroll
                for (int f = 0; f < 4; ++f) {
                    float r = fmaxf(hv[f] * sc, 0.f);
                    unsigned short rb = f2bf(r);
                    float e = bf2f(rb);
                    mh[(size_t)node * 64 + f * 16 + l15] = rb;
                    psum[f] += e;
                    psq[f] += e * e;
                }
            }
        }
    }

#pragma unroll
    for (int f = 0; f < 4; ++f) {
        psum[f] += __shfl_xor(psum[f], 16);
        psum[f] += __shfl_xor(psum[f], 32);
        psq[f] += __shfl_xor(psq[f], 16);
        psq[f] += __shfl_xor(psq[f], 32);
    }
    if (lane < 16) {
#pragma unroll
        for (int f = 0; f < 4; ++f) {
            sRed[wid][f * 16 + l15] = psum[f];
            sRed[wid][64 + f * 16 + l15] = psq[f];
        }
    }
    __syncthreads();
    if (tid < 128) {
        float v = sRed[0][tid] + sRed[1][tid] + sRed[2][tid] + sRed[3][tid];
        pstats[(size_t)blockIdx.x * 128 + tid] = v;
    }

    // ---- last-block-done: reduce pstats -> stats (order-independent, G16-safe)
    if (tid == 0) {
        __threadfence();                       // publish this block's pstats
        int v = atomicAdd(done, 1);            // device-scope ticket
        isLast = (v == fb2 - 1);
    }
    __syncthreads();
    if (isLast) {
        __threadfence();                       // acquire: all pstats visible
        const int col = tid & 127, half = tid >> 7;
        float s = 0.f;
        for (int r = half; r < fb2; r += 2) s += pstats[(size_t)r * 128 + col];
        sP[tid] = s;
        __syncthreads();
        if (tid < 128) stats[tid] = sP[tid] + sP[tid + 128];
    }
}

// ---------------------------------------------------------------- BN-fold + FC
__global__ __launch_bounds__(256) void k_out(
        const unsigned short* __restrict__ h, const float* __restrict__ stats,
        const float* __restrict__ gamma, const float* __restrict__ beta,
        const float* __restrict__ Wfc, const float* __restrict__ bfc,
        float* __restrict__ out, int N) {
    __shared__ float sWm[64 * 16];
    __shared__ float sShift[64];
    __shared__ float sBase[16];
    const int tid = threadIdx.x;
    const float invN = 1.0f / (float)N;
    if (tid < 64) {
        float mu = stats[tid] * invN;
        float var = stats[64 + tid] * invN - mu * mu;
        float sc = gamma[tid] / sqrtf(var + 1e-5f);
        sShift[tid] = beta[tid] - mu * sc;
#pragma unroll
        for (int c = 0; c < 16; ++c) sWm[tid * 16 + c] = Wfc[c * 64 + tid] * sc;
    }
    __syncthreads();
    if (tid < 16) {
        float b = bfc[tid];
#pragma unroll
        for (int j = 0; j < 64; ++j) b += sShift[j] * Wfc[tid * 64 + j];
        sBase[tid] = b;
    }
    __syncthreads();
    int g = blockIdx.x * 256 + tid;
    int n = g >> 4;
    int c = g & 15;
    if (n >= N) return;
    const ushort4* h4 = (const ushort4*)(h + (size_t)n * 64);
    float acc = sBase[c];
#pragma unroll
    for (int jq = 0; jq < 16; ++jq) {
        ushort4 v = h4[jq];
        acc += bf2f(v.x) * sWm[(jq * 4 + 0) * 16 + c];
        acc += bf2f(v.y) * sWm[(jq * 4 + 1) * 16 + c];
        acc += bf2f(v.z) * sWm[(jq * 4 + 2) * 16 + c];
        acc += bf2f(v.w) * sWm[(jq * 4 + 3) * 16 + c];
    }
    out[(size_t)n * 16 + c] = acc;
}

// ============================== host ==============================
extern "C" void kernel_launch(void* const* d_in, const int* in_sizes, int n_in,
                              void* d_out, int out_size, void* d_ws, size_t ws_size,
                              hipStream_t stream) {
    const int* eidx = (const int*)d_in[0];
    const float* x = (const float*)d_in[1];
    const float* Wl = (const float*)d_in[2];
    const float* bl = (const float*)d_in[3];
    const float* Wr = (const float*)d_in[4];
    const float* gamma = (const float*)d_in[5];
    const float* beta = (const float*)d_in[6];
    const float* Wfc = (const float*)d_in[7];
    const float* bfc = (const float*)d_in[8];
    float* out = (float*)d_out;

    const int E = in_sizes[0] / 2;
    const int N = in_sizes[1] / 64;
    const int NB = (N + 511) >> 9;               // <=256 for N<=131072
    const int NBLK = (E + CHUNK - 1) / CHUNK;    // <=256 for E<=2.09M
    const int fb2 = (N + 255) / 256;             // k_fused blocks
    const int n4 = N * 16;

    // layout (4B words):
    int* cnt = (int*)d_ws;                                     // NB*NBLK
    int* btot = cnt + (size_t)NB * NBLK;                       // NB
    int* done = btot + NB;                                     // 1 (+pad NB)
    int* rowptr = done + NB + 1;                               // N+1
    float* pstats = (float*)(rowptr + N + 1);                  // fb2*128
    float* stats = pstats + (size_t)fb2 * 128;                 // 128
    int* colv = (int*)(stats + 128);                           // E
    unsigned int* ebuf = (unsigned int*)(colv + E);            // E
    unsigned short* mh = (unsigned short*)(((uintptr_t)(ebuf + E) + 15) & ~(uintptr_t)15);
    unsigned short* xbf = mh + (size_t)N * 64;                 // N*64 bf16 opt

    size_t need_bf = (size_t)((char*)(xbf + (size_t)N * 64) - (char*)d_ws);
    const int use_bf = (ws_size >= need_bf) ? 1 : 0;

    int cbl = use_bf ? (n4 + 255) / 256 : 0;
    k_prep<<<NBLK + cbl, 256, 0, stream>>>(eidx, cnt, (const float4*)x,
                                           (ushort4*)xbf, done, E, NB, NBLK,
                                           n4, use_bf);
    k_scanbkt<<<NB, 256, 0, stream>>>(cnt, btot, NBLK);
    k_bscatter<<<NBLK, 256, 0, stream>>>(eidx, cnt, btot, ebuf, E, NB, NBLK);
    k_bfinal<<<NB, 256, 0, stream>>>(ebuf, btot, rowptr, colv, N, NB, E);

    int gblocks = (int)(((size_t)N * 16 + 255) / 256);
    if (use_bf) {
        k_gather_bf<<<gblocks, 256, 0, stream>>>((const uint2*)xbf, rowptr, colv,
                                                 (uint2*)mh, N);
    } else {
        k_gather_f32<<<gblocks, 256, 0, stream>>>((const float4*)x, rowptr, colv,
                                                  (ushort4*)mh, N);
    }

    k_fused<<<fb2, 256, 0, stream>>>(x, xbf, use_bf, Wl, bl, Wr, mh,
                                     pstats, stats, done, fb2, N);

    int oblocks = (int)(((size_t)N * 16 + 255) / 256);
    k_out<<<oblocks, 256, 0, stream>>>(mh, stats, gamma, beta, Wfc, bfc, out, N);
}

// Round 4
// 233.267 us; speedup vs baseline: 3.4317x; 1.1562x over previous
//
#include <hip/hip_runtime.h>
#include <hip/hip_bf16.h>

// SAGEConv(mean), 9-dispatch pipeline, zero global atomics:
//   k_prep    = bucket histogram (LDS atomics) + x->bf16 cast, fused
//   k_scanbkt = per-bucket coalesced scan over chunks (rel offsets + btot)
//   k_bscanB  = 1-block scan of bucket totals -> bbase, sentinels
//   k_bscatter= scatter packed (dst&511)<<17|src into bucket segments
//   k_bfinal  = per-bucket LDS counting sort -> rowptr + colv
//   k_gather  = 16-lanes/node CSR gather-mean (6250 blocks: TLP is king)
//   k_fused   = MFMA [mean|x]@[Wl;Wr]^T + L2norm + ReLU + BN partials
//               ** 1 tile/wave, 1563 blocks (was 4 tiles/wave, 391 blocks) **
//   k_stats / k_out
// N=100000, E=1200000, F=H=64, C=16.
//
// Lessons: R4/R5/R7/R8 — device-scope atomics run at the shared coherence
// point; only LDS atomics are cheap. R10 — never shrink the random gather's
// grid. R11 — never serialize a scan into one block to save a launch.
// R12 — uint4/8-lane gather regressed: same per-CU TLP, no win.
// R13 — grid.sync() costs ~200us (1024 blocks spinning on device-scope
// atomics across 8 non-coherent XCD L2s). R14 — last-block-done +
// __threadfence() forces per-block L2 writeback (+45us on k_fused; mh pushed
// to HBM). NEVER trade dispatch boundaries for device-scope sync of any kind.
// R15 (this round): k_fused was OccupancyPercent=7.2%, VALUBusy 4.7%,
// MfmaUtil 0.7% — grid-starved latency-bound. One 16-node tile per wave,
// grid 391->1563 blocks, 6->24 waves/CU. Everything else = R0 exact.

typedef __attribute__((ext_vector_type(8))) short short8;   // 8 bf16
typedef __attribute__((ext_vector_type(4))) float f32x4;

__device__ __forceinline__ unsigned short f2bf(float f) {
    unsigned int u = __builtin_bit_cast(unsigned int, f);
    u += 0x7FFFu + ((u >> 16) & 1u);
    return (unsigned short)(u >> 16);
}
__device__ __forceinline__ float bf2f(unsigned short s) {
    return __builtin_bit_cast(float, ((unsigned int)s) << 16);
}

#define CHUNK 8192

// ---------------- k_prep: blocks [0,NBLK) = bucket hist; rest = x->bf16 cast
__global__ __launch_bounds__(256) void k_prep(const int* __restrict__ eidx,
                                              int* __restrict__ cnt,
                                              const float4* __restrict__ x4,
                                              ushort4* __restrict__ xbf,
                                              int E, int NB, int NBLK,
                                              int n4, int do_x) {
    __shared__ int lh[256];
    const int tid = threadIdx.x;
    if ((int)blockIdx.x < NBLK) {
        lh[tid] = 0;
        __syncthreads();
        const int base = blockIdx.x * CHUNK;
        for (int i = tid; i < CHUNK; i += 256) {
            int e = base + i;
            if (e < E) atomicAdd(&lh[eidx[E + e] >> 9], 1);
        }
        __syncthreads();
        if (tid < NB) cnt[(size_t)tid * NBLK + blockIdx.x] = lh[tid];
    } else if (do_x) {
        int t = ((int)blockIdx.x - NBLK) * 256 + tid;
        if (t < n4) {
            float4 v = x4[t];
            xbf[t] = make_ushort4(f2bf(v.x), f2bf(v.y), f2bf(v.z), f2bf(v.w));
        }
    }
}

// -------- k_scanbkt: one block per bucket; coalesced scan over its chunk row
__global__ __launch_bounds__(256) void k_scanbkt(int* __restrict__ cnt,
                                                 int* __restrict__ btot,
                                                 int NBLK) {
    __shared__ int swv[4];
    const int b = blockIdx.x;
    const int t = threadIdx.x;
    int v = (t < NBLK) ? cnt[(size_t)b * NBLK + t] : 0;
    const int lane = t & 63, wid = t >> 6;
    int s = v;
#pragma unroll
    for (int off = 1; off < 64; off <<= 1) {
        int tt = __shfl_up(s, off);
        if (lane >= off) s += tt;
    }
    if (lane == 63) swv[wid] = s;
    __syncthreads();
    if (t == 0) {
        int a = 0;
#pragma unroll
        for (int w = 0; w < 4; ++w) { int tt = swv[w]; swv[w] = a; a += tt; }
    }
    __syncthreads();
    int excl = s - v + swv[wid];
    if (t < NBLK) cnt[(size_t)b * NBLK + t] = excl;   // relative offset
    if (t == 255) btot[b] = swv[3] + s;               // bucket total
}

// -------- k_bscanB: 1 block; scan bucket totals -> bbase; sentinels
__global__ __launch_bounds__(256) void k_bscanB(const int* __restrict__ btot,
                                                int* __restrict__ bbase,
                                                int* __restrict__ rowptr,
                                                int NB, int N, int E) {
    __shared__ int swv[4];
    const int t = threadIdx.x;
    int v = (t < NB) ? btot[t] : 0;
    const int lane = t & 63, wid = t >> 6;
    int s = v;
#pragma unroll
    for (int off = 1; off < 64; off <<= 1) {
        int tt = __shfl_up(s, off);
        if (lane >= off) s += tt;
    }
    if (lane == 63) swv[wid] = s;
    __syncthreads();
    if (t == 0) {
        int a = 0;
#pragma unroll
        for (int w = 0; w < 4; ++w) { int tt = swv[w]; swv[w] = a; a += tt; }
    }
    __syncthreads();
    if (t < NB) bbase[t] = s - v + swv[wid];
    if (t == 0) { bbase[NB] = E; rowptr[N] = E; }
}

// ---------------- k_bscatter: packed edges into bucket segments (LDS cursors)
__global__ __launch_bounds__(256) void k_bscatter(const int* __restrict__ eidx,
                                                  const int* __restrict__ cnt,
                                                  const int* __restrict__ bbase,
                                                  unsigned int* __restrict__ ebuf,
                                                  int E, int NB, int NBLK) {
    __shared__ int cur[256];
    const int tid = threadIdx.x;
    if (tid < NB)
        cur[tid] = bbase[tid] + cnt[(size_t)tid * NBLK + blockIdx.x];
    __syncthreads();
    const int base = blockIdx.x * CHUNK;
    for (int i = tid; i < CHUNK; i += 256) {
        int e = base + i;
        if (e < E) {
            int d = eidx[E + e];
            int s = eidx[e];
            int p = atomicAdd(&cur[d >> 9], 1);
            ebuf[p] = (unsigned int)s | ((unsigned int)(d & 511) << 17);
        }
    }
}

// ---------------- k_bfinal: per-bucket LDS hist + scan -> rowptr + colv
__global__ __launch_bounds__(256) void k_bfinal(const unsigned int* __restrict__ ebuf,
                                                const int* __restrict__ bbase,
                                                int* __restrict__ rowptr,
                                                int* __restrict__ colv, int N) {
    __shared__ int h[512];
    __shared__ int swv[4];
    const int b = blockIdx.x;
    const int tid = threadIdx.x;
    h[2 * tid] = 0;
    h[2 * tid + 1] = 0;
    __syncthreads();
    const int segb = bbase[b], sege = bbase[b + 1];
    for (int i = segb + tid; i < sege; i += 256)
        atomicAdd(&h[ebuf[i] >> 17], 1);
    __syncthreads();
    int a0 = h[2 * tid], a1 = h[2 * tid + 1];
    int ts = a0 + a1;
    const int lane = tid & 63, wid = tid >> 6;
    int s = ts;
#pragma unroll
    for (int off = 1; off < 64; off <<= 1) {
        int tt = __shfl_up(s, off);
        if (lane >= off) s += tt;
    }
    if (lane == 63) swv[wid] = s;
    __syncthreads();
    if (tid == 0) {
        int a = 0;
#pragma unroll
        for (int w = 0; w < 4; ++w) { int tt = swv[w]; swv[w] = a; a += tt; }
    }
    __syncthreads();
    int excl = s - ts + swv[wid];
    h[2 * tid] = excl;
    h[2 * tid + 1] = excl + a0;
    int node = b * 512 + 2 * tid;
    if (node < N) rowptr[node] = segb + excl;
    if (node + 1 < N) rowptr[node + 1] = segb + excl + a0;
    __syncthreads();
    for (int i = segb + tid; i < sege; i += 256) {
        unsigned int u = ebuf[i];
        int p = atomicAdd(&h[u >> 17], 1);
        colv[segb + p] = (int)(u & 0x1FFFFu);
    }
}

// -------------- gather-mean (bf16 x): 16 lanes/node, full occupancy
__global__ __launch_bounds__(256) void k_gather_bf(
        const uint2* __restrict__ xbf2, const int* __restrict__ rowptr,
        const int* __restrict__ colv, uint2* __restrict__ mh2, int N) {
    int t = blockIdx.x * 256 + threadIdx.x;
    int n = t >> 4;
    int l = t & 15;
    if (n >= N) return;
    int b = rowptr[n], e = rowptr[n + 1];
    float a0 = 0.f, a1 = 0.f, a2 = 0.f, a3 = 0.f;
    int p = b;
    for (; p + 4 <= e; p += 4) {
        int s0 = colv[p], s1 = colv[p + 1], s2 = colv[p + 2], s3 = colv[p + 3];
        uint2 v0 = xbf2[(size_t)s0 * 16 + l];
        uint2 v1 = xbf2[(size_t)s1 * 16 + l];
        uint2 v2 = xbf2[(size_t)s2 * 16 + l];
        uint2 v3 = xbf2[(size_t)s3 * 16 + l];
        a0 += bf2f((unsigned short)(v0.x & 0xFFFF)) + bf2f((unsigned short)(v1.x & 0xFFFF)) +
              bf2f((unsigned short)(v2.x & 0xFFFF)) + bf2f((unsigned short)(v3.x & 0xFFFF));
        a1 += bf2f((unsigned short)(v0.x >> 16)) + bf2f((unsigned short)(v1.x >> 16)) +
              bf2f((unsigned short)(v2.x >> 16)) + bf2f((unsigned short)(v3.x >> 16));
        a2 += bf2f((unsigned short)(v0.y & 0xFFFF)) + bf2f((unsigned short)(v1.y & 0xFFFF)) +
              bf2f((unsigned short)(v2.y & 0xFFFF)) + bf2f((unsigned short)(v3.y & 0xFFFF));
        a3 += bf2f((unsigned short)(v0.y >> 16)) + bf2f((unsigned short)(v1.y >> 16)) +
              bf2f((unsigned short)(v2.y >> 16)) + bf2f((unsigned short)(v3.y >> 16));
    }
    for (; p < e; ++p) {
        int s0 = colv[p];
        uint2 v0 = xbf2[(size_t)s0 * 16 + l];
        a0 += bf2f((unsigned short)(v0.x & 0xFFFF));
        a1 += bf2f((unsigned short)(v0.x >> 16));
        a2 += bf2f((unsigned short)(v0.y & 0xFFFF));
        a3 += bf2f((unsigned short)(v0.y >> 16));
    }
    float inv = 1.0f / fmaxf((float)(e - b), 1.0f);
    uint2 o;
    o.x = (unsigned int)f2bf(a0 * inv) | ((unsigned int)f2bf(a1 * inv) << 16);
    o.y = (unsigned int)f2bf(a2 * inv) | ((unsigned int)f2bf(a3 * inv) << 16);
    mh2[(size_t)n * 16 + l] = o;
}

// ------------------------- gather-mean (f32 x fallback, if ws too small)
__global__ __launch_bounds__(256) void k_gather_f32(
        const float4* __restrict__ x4, const int* __restrict__ rowptr,
        const int* __restrict__ colv, ushort4* __restrict__ mh, int N) {
    int t = blockIdx.x * 256 + threadIdx.x;
    int n = t >> 4;
    int l = t & 15;
    if (n >= N) return;
    int b = rowptr[n], e = rowptr[n + 1];
    float ax = 0.f, ay = 0.f, az = 0.f, aw = 0.f;
    int p = b;
    for (; p + 4 <= e; p += 4) {
        int s0 = colv[p], s1 = colv[p + 1], s2 = colv[p + 2], s3 = colv[p + 3];
        float4 v0 = x4[(size_t)s0 * 16 + l];
        float4 v1 = x4[(size_t)s1 * 16 + l];
        float4 v2 = x4[(size_t)s2 * 16 + l];
        float4 v3 = x4[(size_t)s3 * 16 + l];
        ax += (v0.x + v1.x) + (v2.x + v3.x);
        ay += (v0.y + v1.y) + (v2.y + v3.y);
        az += (v0.z + v1.z) + (v2.z + v3.z);
        aw += (v0.w + v1.w) + (v2.w + v3.w);
    }
    for (; p < e; ++p) {
        int s0 = colv[p];
        float4 v0 = x4[(size_t)s0 * 16 + l];
        ax += v0.x; ay += v0.y; az += v0.z; aw += v0.w;
    }
    float inv = 1.0f / fmaxf((float)(e - b), 1.0f);
    mh[(size_t)n * 16 + l] = make_ushort4(f2bf(ax * inv), f2bf(ay * inv),
                                          f2bf(az * inv), f2bf(aw * inv));
}

// --------- k_fused: MFMA [mean|x]@[Wl;Wr]^T + bl, L2norm, ReLU, BN partials.
// R15: ONE 16-node tile per wave (64 nodes/block, 1563 blocks) — fixes the
// measured 7.2% occupancy / 86us latency-bound profile of the 4-tile version.
__global__ __launch_bounds__(256) void k_fused(
        const float* __restrict__ x,
        const unsigned short* __restrict__ xbf, int use_bf,
        const float* __restrict__ Wl, const float* __restrict__ bl,
        const float* __restrict__ Wr,
        unsigned short* __restrict__ mh,   // in: bf16 mean; out: bf16 h
        float* __restrict__ pstats, int N) {
    __shared__ float sRed[4][128];

    const int tid = threadIdx.x;
    const int wid = tid >> 6;
    const int lane = tid & 63;
    const int l15 = lane & 15;
    const int quad = lane >> 4;

    short8 bfrag[4][4];
#pragma unroll
    for (int c = 0; c < 4; ++c) {
#pragma unroll
        for (int f = 0; f < 4; ++f) {
            const int n = f * 16 + l15;
            const float* wsrc = (c < 2)
                ? (Wl + (size_t)n * 64 + c * 32 + quad * 8)
                : (Wr + (size_t)n * 64 + (c - 2) * 32 + quad * 8);
            float4 w0 = *(const float4*)wsrc;
            float4 w1 = *(const float4*)(wsrc + 4);
            union { short8 v; unsigned short u[8]; } pk;
            pk.u[0] = f2bf(w0.x); pk.u[1] = f2bf(w0.y);
            pk.u[2] = f2bf(w0.z); pk.u[3] = f2bf(w0.w);
            pk.u[4] = f2bf(w1.x); pk.u[5] = f2bf(w1.y);
            pk.u[6] = f2bf(w1.z); pk.u[7] = f2bf(w1.w);
            bfrag[c][f] = pk.v;
        }
    }

    float blv[4];
#pragma unroll
    for (int f = 0; f < 4; ++f) blv[f] = bl[f * 16 + l15];

    float psum[4] = {0.f, 0.f, 0.f, 0.f};
    float psq[4] = {0.f, 0.f, 0.f, 0.f};

    const int tbase = blockIdx.x * 64 + wid * 16;
    const int mrow = tbase + l15;
    const int mld = (mrow < N) ? mrow : (N - 1);
    f32x4 acc[4] = {{0.f, 0.f, 0.f, 0.f}, {0.f, 0.f, 0.f, 0.f},
                    {0.f, 0.f, 0.f, 0.f}, {0.f, 0.f, 0.f, 0.f}};
#pragma unroll
    for (int c = 0; c < 2; ++c) {
        short8 a = *(const short8*)(mh + (size_t)mld * 64 + c * 32 + quad * 8);
#pragma unroll
        for (int f = 0; f < 4; ++f)
            acc[f] = __builtin_amdgcn_mfma_f32_16x16x32_bf16(a, bfrag[c][f], acc[f], 0, 0, 0);
    }
    if (use_bf) {
#pragma unroll
        for (int c = 0; c < 2; ++c) {
            short8 a = *(const short8*)(xbf + (size_t)mld * 64 + c * 32 + quad * 8);
#pragma unroll
            for (int f = 0; f < 4; ++f)
                acc[f] = __builtin_amdgcn_mfma_f32_16x16x32_bf16(a, bfrag[c + 2][f], acc[f], 0, 0, 0);
        }
    } else {
#pragma unroll
        for (int c = 0; c < 2; ++c) {
            const float* xp = x + (size_t)mld * 64 + c * 32 + quad * 8;
            float4 a0 = *(const float4*)xp;
            float4 a1 = *(const float4*)(xp + 4);
            union { short8 v; unsigned short u[8]; } pk;
            pk.u[0] = f2bf(a0.x); pk.u[1] = f2bf(a0.y);
            pk.u[2] = f2bf(a0.z); pk.u[3] = f2bf(a0.w);
            pk.u[4] = f2bf(a1.x); pk.u[5] = f2bf(a1.y);
            pk.u[6] = f2bf(a1.z); pk.u[7] = f2bf(a1.w);
#pragma unroll
            for (int f = 0; f < 4; ++f)
                acc[f] = __builtin_amdgcn_mfma_f32_16x16x32_bf16(pk.v, bfrag[c + 2][f], acc[f], 0, 0, 0);
        }
    }

#pragma unroll
    for (int reg = 0; reg < 4; ++reg) {
        const int node = tbase + quad * 4 + reg;
        float hv[4];
        float ss = 0.f;
#pragma unroll
        for (int f = 0; f < 4; ++f) {
            hv[f] = acc[f][reg] + blv[f];
            ss += hv[f] * hv[f];
        }
        ss += __shfl_xor(ss, 1);
        ss += __shfl_xor(ss, 2);
        ss += __shfl_xor(ss, 4);
        ss += __shfl_xor(ss, 8);
        float sc = 1.0f / fmaxf(sqrtf(ss), 1e-12f);
        if (node < N) {
#pragma unroll
            for (int f = 0; f < 4; ++f) {
                float r = fmaxf(hv[f] * sc, 0.f);
                unsigned short rb = f2bf(r);
                float e = bf2f(rb);
                mh[(size_t)node * 64 + f * 16 + l15] = rb;
                psum[f] += e;
                psq[f] += e * e;
            }
        }
    }

#pragma unroll
    for (int f = 0; f < 4; ++f) {
        psum[f] += __shfl_xor(psum[f], 16);
        psum[f] += __shfl_xor(psum[f], 32);
        psq[f] += __shfl_xor(psq[f], 16);
        psq[f] += __shfl_xor(psq[f], 32);
    }
    if (lane < 16) {
#pragma unroll
        for (int f = 0; f < 4; ++f) {
            sRed[wid][f * 16 + l15] = psum[f];
            sRed[wid][64 + f * 16 + l15] = psq[f];
        }
    }
    __syncthreads();
    if (tid < 128) {
        float v = sRed[0][tid] + sRed[1][tid] + sRed[2][tid] + sRed[3][tid];
        pstats[(size_t)blockIdx.x * 128 + tid] = v;
    }
}

// ---------------------------------------------- reduce per-block BN partials
__global__ __launch_bounds__(64) void k_stats(const float* __restrict__ pstats,
                                              float* __restrict__ stats, int nblk) {
    int col = blockIdx.x;
    int l = threadIdx.x;
    float s = 0.f;
    for (int r = l; r < nblk; r += 64) s += pstats[(size_t)r * 128 + col];
    s += __shfl_xor(s, 1);
    s += __shfl_xor(s, 2);
    s += __shfl_xor(s, 4);
    s += __shfl_xor(s, 8);
    s += __shfl_xor(s, 16);
    s += __shfl_xor(s, 32);
    if (l == 0) stats[col] = s;
}

// ---------------------------------------------------------------- BN-fold + FC
__global__ __launch_bounds__(256) void k_out(
        const unsigned short* __restrict__ h, const float* __restrict__ stats,
        const float* __restrict__ gamma, const float* __restrict__ beta,
        const float* __restrict__ Wfc, const float* __restrict__ bfc,
        float* __restrict__ out, int N) {
    __shared__ float sWm[64 * 16];
    __shared__ float sShift[64];
    __shared__ float sBase[16];
    const int tid = threadIdx.x;
    const float invN = 1.0f / (float)N;
    if (tid < 64) {
        float mu = stats[tid] * invN;
        float var = stats[64 + tid] * invN - mu * mu;
        float sc = gamma[tid] / sqrtf(var + 1e-5f);
        sShift[tid] = beta[tid] - mu * sc;
#pragma unroll
        for (int c = 0; c < 16; ++c) sWm[tid * 16 + c] = Wfc[c * 64 + tid] * sc;
    }
    __syncthreads();
    if (tid < 16) {
        float b = bfc[tid];
#pragma unroll
        for (int j = 0; j < 64; ++j) b += sShift[j] * Wfc[tid * 64 + j];
        sBase[tid] = b;
    }
    __syncthreads();
    int g = blockIdx.x * 256 + tid;
    int n = g >> 4;
    int c = g & 15;
    if (n >= N) return;
    const ushort4* h4 = (const ushort4*)(h + (size_t)n * 64);
    float acc = sBase[c];
#pragma unroll
    for (int jq = 0; jq < 16; ++jq) {
        ushort4 v = h4[jq];
        acc += bf2f(v.x) * sWm[(jq * 4 + 0) * 16 + c];
        acc += bf2f(v.y) * sWm[(jq * 4 + 1) * 16 + c];
        acc += bf2f(v.z) * sWm[(jq * 4 + 2) * 16 + c];
        acc += bf2f(v.w) * sWm[(jq * 4 + 3) * 16 + c];
    }
    out[(size_t)n * 16 + c] = acc;
}

extern "C" void kernel_launch(void* const* d_in, const int* in_sizes, int n_in,
                              void* d_out, int out_size, void* d_ws, size_t ws_size,
                              hipStream_t stream) {
    const int* eidx = (const int*)d_in[0];
    const float* x = (const float*)d_in[1];
    const float* Wl = (const float*)d_in[2];
    const float* bl = (const float*)d_in[3];
    const float* Wr = (const float*)d_in[4];
    const float* gamma = (const float*)d_in[5];
    const float* beta = (const float*)d_in[6];
    const float* Wfc = (const float*)d_in[7];
    const float* bfc = (const float*)d_in[8];
    float* out = (float*)d_out;

    const int E = in_sizes[0] / 2;
    const int N = in_sizes[1] / 64;
    const int NB = (N + 511) >> 9;               // <=256 for N<=131072
    const int NBLK = (E + CHUNK - 1) / CHUNK;    // <=256 for E<=2.09M
    const int fb2 = (N + 63) / 64;               // k_fused blocks (64 nodes/blk)
    const int n4 = N * 16;

    // layout (4B words):
    int* cnt = (int*)d_ws;                                     // NB*NBLK
    int* btot = cnt + (size_t)NB * NBLK;                       // NB
    int* bbase = btot + NB;                                    // NB+1
    int* rowptr = bbase + NB + 1;                              // N+1
    float* pstats = (float*)(rowptr + N + 1);                  // fb2*128
    float* stats = pstats + (size_t)fb2 * 128;                 // 128
    int* colv = (int*)(stats + 128);                           // E
    unsigned int* ebuf = (unsigned int*)(colv + E);            // E
    unsigned short* mh = (unsigned short*)(((uintptr_t)(ebuf + E) + 15) & ~(uintptr_t)15);
    unsigned short* xbf = mh + (size_t)N * 64;                 // N*64 bf16 opt

    size_t need_bf = (size_t)((char*)(xbf + (size_t)N * 64) - (char*)d_ws);
    const int use_bf = (ws_size >= need_bf) ? 1 : 0;

    int cbl = use_bf ? (n4 + 255) / 256 : 0;
    k_prep<<<NBLK + cbl, 256, 0, stream>>>(eidx, cnt, (const float4*)x,
                                           (ushort4*)xbf, E, NB, NBLK, n4, use_bf);
    k_scanbkt<<<NB, 256, 0, stream>>>(cnt, btot, NBLK);
    k_bscanB<<<1, 256, 0, stream>>>(btot, bbase, rowptr, NB, N, E);
    k_bscatter<<<NBLK, 256, 0, stream>>>(eidx, cnt, bbase, ebuf, E, NB, NBLK);
    k_bfinal<<<NB, 256, 0, stream>>>(ebuf, bbase, rowptr, colv, N);

    int gblocks = (int)(((size_t)N * 16 + 255) / 256);
    if (use_bf) {
        k_gather_bf<<<gblocks, 256, 0, stream>>>((const uint2*)xbf, rowptr, colv,
                                                 (uint2*)mh, N);
    } else {
        k_gather_f32<<<gblocks, 256, 0, stream>>>((const float4*)x, rowptr, colv,
                                                  (ushort4*)mh, N);
    }

    k_fused<<<fb2, 256, 0, stream>>>(x, xbf, use_bf, Wl, bl, Wr, mh, pstats, N);
    k_stats<<<128, 64, 0, stream>>>(pstats, stats, fb2);

    int oblocks = (int)(((size_t)N * 16 + 255) / 256);
    k_out<<<oblocks, 256, 0, stream>>>(mh, stats, gamma, beta, Wfc, bfc, out, N);
}

// Round 5
// 231.022 us; speedup vs baseline: 3.4650x; 1.0097x over previous
//
#include <hip/hip_runtime.h>
#include <hip/hip_bf16.h>

// SAGEConv(mean), 7-dispatch pipeline, zero global atomics, zero grid syncs:
//   k_prep    = bucket histogram (LDS atomics) + x->bf16 cast, fused
//   k_scanbkt = per-bucket coalesced scan over chunks (rel offsets + btot)
//   k_bscatter= in-block bbase rebuild (scan btot) + scatter packed edges
//   k_bfinal  = in-block bbase rebuild + per-bucket LDS counting sort
//   k_gfused  = gather-mean DIRECTLY into MFMA A-fragments (4 lanes/node,
//               lane-quad owns feat slices {q*8..+8},{32+q*8..+8}) +
//               MFMA [mean|x]@[Wl;Wr]^T + L2norm + ReLU + BN partials.
//               No mh mean round-trip (-25MB), no LDS transpose, -1 boundary.
//   k_stats / k_out
// N=100000, E=1200000, F=H=64, C=16.
//
// Lessons: R4/R5/R7/R8 — device-scope atomics run at the shared coherence
// point; only LDS atomics are cheap. R10 — never shrink the random gather's
// TLP below saturation. R11 — never serialize a scan into one block.
// R12 — uint4/8-lane standalone gather: no win (same per-CU TLP).
// R13 — grid.sync() ~200us (spin on device-scope atomics across 8
// non-coherent XCD L2s). R14 — per-block __threadfence() release forces L2
// writeback (+45us). NEVER trade boundaries for device-scope sync.
// R15 — k_fused 4-tile was occupancy-starved (7.2%/86us); 1-tile fixed it
// (left top-5) but wall noise is +-10us: only >=20us targets are testable.
// R16 (this round): boundaries ~10us x8 is the last modeled whale; merge by
// DATA FLOW only: gather fused into MFMA kernel + bscanB killed by in-block
// rebuild (both pieces individually harness-proven).

typedef __attribute__((ext_vector_type(8))) short short8;   // 8 bf16
typedef __attribute__((ext_vector_type(4))) float f32x4;

__device__ __forceinline__ unsigned short f2bf(float f) {
    unsigned int u = __builtin_bit_cast(unsigned int, f);
    u += 0x7FFFu + ((u >> 16) & 1u);
    return (unsigned short)(u >> 16);
}
__device__ __forceinline__ float bf2f(unsigned short s) {
    return __builtin_bit_cast(float, ((unsigned int)s) << 16);
}

#define CHUNK 8192

// 256-thread exclusive scan; all 256 threads of the block must call.
__device__ __forceinline__ int exclScan256(int v, int* swv) {
    const int t = threadIdx.x, lane = t & 63, wid = t >> 6;
    __syncthreads();
    int s = v;
#pragma unroll
    for (int off = 1; off < 64; off <<= 1) {
        int tt = __shfl_up(s, off);
        if (lane >= off) s += tt;
    }
    if (lane == 63) swv[wid] = s;
    __syncthreads();
    if (t == 0) {
        int a = 0;
#pragma unroll
        for (int w = 0; w < 4; ++w) { int tt = swv[w]; swv[w] = a; a += tt; }
    }
    __syncthreads();
    return s - v + swv[wid];
}

// ---------------- k_prep: blocks [0,NBLK) = bucket hist; rest = x->bf16 cast
__global__ __launch_bounds__(256) void k_prep(const int* __restrict__ eidx,
                                              int* __restrict__ cnt,
                                              const float4* __restrict__ x4,
                                              ushort4* __restrict__ xbf,
                                              int E, int NB, int NBLK,
                                              int n4, int do_x) {
    __shared__ int lh[256];
    const int tid = threadIdx.x;
    if ((int)blockIdx.x < NBLK) {
        lh[tid] = 0;
        __syncthreads();
        const int base = blockIdx.x * CHUNK;
        for (int i = tid; i < CHUNK; i += 256) {
            int e = base + i;
            if (e < E) atomicAdd(&lh[eidx[E + e] >> 9], 1);
        }
        __syncthreads();
        if (tid < NB) cnt[(size_t)tid * NBLK + blockIdx.x] = lh[tid];
    } else if (do_x) {
        int t = ((int)blockIdx.x - NBLK) * 256 + tid;
        if (t < n4) {
            float4 v = x4[t];
            xbf[t] = make_ushort4(f2bf(v.x), f2bf(v.y), f2bf(v.z), f2bf(v.w));
        }
    }
}

// -------- k_scanbkt: one block per bucket; coalesced scan over its chunk row
__global__ __launch_bounds__(256) void k_scanbkt(int* __restrict__ cnt,
                                                 int* __restrict__ btot,
                                                 int NBLK) {
    __shared__ int swv[4];
    const int b = blockIdx.x;
    const int t = threadIdx.x;
    int v = (t < NBLK) ? cnt[(size_t)b * NBLK + t] : 0;
    int excl = exclScan256(v, swv);
    if (t < NBLK) cnt[(size_t)b * NBLK + t] = excl;   // relative offset
    if (t == 255) btot[b] = excl + v;                 // bucket total
}

// ------ k_bscatter: in-block bbase rebuild (scan btot) + scatter to segments
__global__ __launch_bounds__(256) void k_bscatter(const int* __restrict__ eidx,
                                                  const int* __restrict__ cnt,
                                                  const int* __restrict__ btot,
                                                  unsigned int* __restrict__ ebuf,
                                                  int E, int NB, int NBLK) {
    __shared__ int cur[256];
    __shared__ int swv[4];
    const int tid = threadIdx.x;
    int bv = (tid < NB) ? btot[tid] : 0;
    int bexcl = exclScan256(bv, swv);
    if (tid < NB)
        cur[tid] = bexcl + cnt[(size_t)tid * NBLK + blockIdx.x];
    __syncthreads();
    const int base = blockIdx.x * CHUNK;
    for (int i = tid; i < CHUNK; i += 256) {
        int e = base + i;
        if (e < E) {
            int d = eidx[E + e];
            int s = eidx[e];
            int p = atomicAdd(&cur[d >> 9], 1);
            ebuf[p] = (unsigned int)s | ((unsigned int)(d & 511) << 17);
        }
    }
}

// ---- k_bfinal: in-block bbase rebuild + per-bucket LDS counting sort
__global__ __launch_bounds__(256) void k_bfinal(const unsigned int* __restrict__ ebuf,
                                                const int* __restrict__ btot,
                                                int* __restrict__ rowptr,
                                                int* __restrict__ colv,
                                                int N, int NB, int E) {
    __shared__ int h[512];
    __shared__ int swv[4];
    __shared__ int sseg[2];
    const int b = blockIdx.x;
    const int tid = threadIdx.x;
    int bv = (tid < NB) ? btot[tid] : 0;
    int bexcl = exclScan256(bv, swv);
    if (tid == b) { sseg[0] = bexcl; sseg[1] = bexcl + bv; }   // b < NB <= 256
    h[2 * tid] = 0;
    h[2 * tid + 1] = 0;
    __syncthreads();
    const int segb = sseg[0], sege = sseg[1];
    for (int i = segb + tid; i < sege; i += 256)
        atomicAdd(&h[ebuf[i] >> 17], 1);
    __syncthreads();
    int a0 = h[2 * tid], a1 = h[2 * tid + 1];
    int ts = a0 + a1;
    const int lane = tid & 63, wid = tid >> 6;
    int s = ts;
#pragma unroll
    for (int off = 1; off < 64; off <<= 1) {
        int tt = __shfl_up(s, off);
        if (lane >= off) s += tt;
    }
    if (lane == 63) swv[wid] = s;
    __syncthreads();
    if (tid == 0) {
        int a = 0;
#pragma unroll
        for (int w = 0; w < 4; ++w) { int tt = swv[w]; swv[w] = a; a += tt; }
    }
    __syncthreads();
    int excl = s - ts + swv[wid];
    h[2 * tid] = excl;
    h[2 * tid + 1] = excl + a0;
    int node = b * 512 + 2 * tid;
    if (node < N) rowptr[node] = segb + excl;
    if (node + 1 < N) rowptr[node + 1] = segb + excl + a0;
    __syncthreads();
    for (int i = segb + tid; i < sege; i += 256) {
        unsigned int u = ebuf[i];
        int p = atomicAdd(&h[u >> 17], 1);
        colv[segb + p] = (int)(u & 0x1FFFFu);
    }
    if (b == 0 && tid == 0) rowptr[N] = E;
}

// -------- acc8: accumulate 8 bf16 (one uint4) into f32[8]
__device__ __forceinline__ void acc8(float a[8], uint4 v) {
    a[0] += bf2f((unsigned short)(v.x & 0xFFFFu));
    a[1] += bf2f((unsigned short)(v.x >> 16));
    a[2] += bf2f((unsigned short)(v.y & 0xFFFFu));
    a[3] += bf2f((unsigned short)(v.y >> 16));
    a[4] += bf2f((unsigned short)(v.z & 0xFFFFu));
    a[5] += bf2f((unsigned short)(v.z >> 16));
    a[6] += bf2f((unsigned short)(v.w & 0xFFFFu));
    a[7] += bf2f((unsigned short)(v.w >> 16));
}

// ===== k_gfused: gather-mean into A-fragments + MFMA + L2norm + ReLU + BN.
// One 16-node tile per wave (64 nodes/block). Lane (l15,quad): node = l15,
// owns feature slices {quad*8..+8} (c=0) and {32+quad*8..+8} (c=1) — the
// exact MFMA A-fragment layout, so the gathered mean never leaves registers.
__global__ __launch_bounds__(256) void k_gfused(
        const unsigned short* __restrict__ xbf,
        const int* __restrict__ rowptr, const int* __restrict__ colv,
        const float* __restrict__ Wl, const float* __restrict__ bl,
        const float* __restrict__ Wr,
        unsigned short* __restrict__ mh,   // out: bf16 h
        float* __restrict__ pstats, int N) {
    __shared__ float sRed[4][128];

    const int tid = threadIdx.x;
    const int wid = tid >> 6;
    const int lane = tid & 63;
    const int l15 = lane & 15;
    const int quad = lane >> 4;

    const int tbase = blockIdx.x * 64 + wid * 16;
    const int mrow = tbase + l15;
    const int mld = (mrow < N) ? mrow : (N - 1);

    // ---- gather phase (low VGPR; weights staged after to keep ranges disjoint)
    const int gb = rowptr[mld], ge = rowptr[mld + 1];
    float g0[8], g1[8];
#pragma unroll
    for (int j = 0; j < 8; ++j) { g0[j] = 0.f; g1[j] = 0.f; }
    const unsigned short* xrow = xbf + quad * 8;
    int p = gb;
    for (; p + 2 <= ge; p += 2) {
        int s0 = colv[p], s1 = colv[p + 1];
        uint4 v00 = *(const uint4*)(xrow + (size_t)s0 * 64);
        uint4 v01 = *(const uint4*)(xrow + (size_t)s0 * 64 + 32);
        uint4 v10 = *(const uint4*)(xrow + (size_t)s1 * 64);
        uint4 v11 = *(const uint4*)(xrow + (size_t)s1 * 64 + 32);
        acc8(g0, v00); acc8(g1, v01);
        acc8(g0, v10); acc8(g1, v11);
    }
    for (; p < ge; ++p) {
        int s0 = colv[p];
        uint4 v00 = *(const uint4*)(xrow + (size_t)s0 * 64);
        uint4 v01 = *(const uint4*)(xrow + (size_t)s0 * 64 + 32);
        acc8(g0, v00); acc8(g1, v01);
    }
    const float inv = 1.0f / fmaxf((float)(ge - gb), 1.0f);
    short8 afr[2];
    {
        union { short8 v; unsigned short u[8]; } pk;
#pragma unroll
        for (int j = 0; j < 8; ++j) pk.u[j] = f2bf(g0[j] * inv);
        afr[0] = pk.v;
#pragma unroll
        for (int j = 0; j < 8; ++j) pk.u[j] = f2bf(g1[j] * inv);
        afr[1] = pk.v;
    }

    // ---- root-path A-fragments (x itself, bf16)
    short8 rfr[2];
    rfr[0] = *(const short8*)(xbf + (size_t)mld * 64 + quad * 8);
    rfr[1] = *(const short8*)(xbf + (size_t)mld * 64 + 32 + quad * 8);

    // ---- weight fragments [Wl;Wr] (B operand), bias
    short8 bfrag[4][4];
#pragma unroll
    for (int c = 0; c < 4; ++c) {
#pragma unroll
        for (int f = 0; f < 4; ++f) {
            const int n = f * 16 + l15;
            const float* wsrc = (c < 2)
                ? (Wl + (size_t)n * 64 + c * 32 + quad * 8)
                : (Wr + (size_t)n * 64 + (c - 2) * 32 + quad * 8);
            float4 w0 = *(const float4*)wsrc;
            float4 w1 = *(const float4*)(wsrc + 4);
            union { short8 v; unsigned short u[8]; } pk;
            pk.u[0] = f2bf(w0.x); pk.u[1] = f2bf(w0.y);
            pk.u[2] = f2bf(w0.z); pk.u[3] = f2bf(w0.w);
            pk.u[4] = f2bf(w1.x); pk.u[5] = f2bf(w1.y);
            pk.u[6] = f2bf(w1.z); pk.u[7] = f2bf(w1.w);
            bfrag[c][f] = pk.v;
        }
    }
    float blv[4];
#pragma unroll
    for (int f = 0; f < 4; ++f) blv[f] = bl[f * 16 + l15];

    // ---- MFMA
    f32x4 acc[4] = {{0.f, 0.f, 0.f, 0.f}, {0.f, 0.f, 0.f, 0.f},
                    {0.f, 0.f, 0.f, 0.f}, {0.f, 0.f, 0.f, 0.f}};
#pragma unroll
    for (int c = 0; c < 2; ++c)
#pragma unroll
        for (int f = 0; f < 4; ++f)
            acc[f] = __builtin_amdgcn_mfma_f32_16x16x32_bf16(afr[c], bfrag[c][f], acc[f], 0, 0, 0);
#pragma unroll
    for (int c = 0; c < 2; ++c)
#pragma unroll
        for (int f = 0; f < 4; ++f)
            acc[f] = __builtin_amdgcn_mfma_f32_16x16x32_bf16(rfr[c], bfrag[c + 2][f], acc[f], 0, 0, 0);

    // ---- epilogue: +bias, L2 norm, ReLU, store h, BN partials
    float psum[4] = {0.f, 0.f, 0.f, 0.f};
    float psq[4] = {0.f, 0.f, 0.f, 0.f};
#pragma unroll
    for (int reg = 0; reg < 4; ++reg) {
        const int node = tbase + quad * 4 + reg;
        float hv[4];
        float ss = 0.f;
#pragma unroll
        for (int f = 0; f < 4; ++f) {
            hv[f] = acc[f][reg] + blv[f];
            ss += hv[f] * hv[f];
        }
        ss += __shfl_xor(ss, 1);
        ss += __shfl_xor(ss, 2);
        ss += __shfl_xor(ss, 4);
        ss += __shfl_xor(ss, 8);
        float sc = 1.0f / fmaxf(sqrtf(ss), 1e-12f);
        if (node < N) {
#pragma unroll
            for (int f = 0; f < 4; ++f) {
                float r = fmaxf(hv[f] * sc, 0.f);
                unsigned short rb = f2bf(r);
                float e = bf2f(rb);
                mh[(size_t)node * 64 + f * 16 + l15] = rb;
                psum[f] += e;
                psq[f] += e * e;
            }
        }
    }

#pragma unroll
    for (int f = 0; f < 4; ++f) {
        psum[f] += __shfl_xor(psum[f], 16);
        psum[f] += __shfl_xor(psum[f], 32);
        psq[f] += __shfl_xor(psq[f], 16);
        psq[f] += __shfl_xor(psq[f], 32);
    }
    if (lane < 16) {
#pragma unroll
        for (int f = 0; f < 4; ++f) {
            sRed[wid][f * 16 + l15] = psum[f];
            sRed[wid][64 + f * 16 + l15] = psq[f];
        }
    }
    __syncthreads();
    if (tid < 128) {
        float v = sRed[0][tid] + sRed[1][tid] + sRed[2][tid] + sRed[3][tid];
        pstats[(size_t)blockIdx.x * 128 + tid] = v;
    }
}

// ---------------- fallback path (ws too small for xbf): f32 gather + fused
__global__ __launch_bounds__(256) void k_gather_f32(
        const float4* __restrict__ x4, const int* __restrict__ rowptr,
        const int* __restrict__ colv, ushort4* __restrict__ mh, int N) {
    int t = blockIdx.x * 256 + threadIdx.x;
    int n = t >> 4;
    int l = t & 15;
    if (n >= N) return;
    int b = rowptr[n], e = rowptr[n + 1];
    float ax = 0.f, ay = 0.f, az = 0.f, aw = 0.f;
    int p = b;
    for (; p + 4 <= e; p += 4) {
        int s0 = colv[p], s1 = colv[p + 1], s2 = colv[p + 2], s3 = colv[p + 3];
        float4 v0 = x4[(size_t)s0 * 16 + l];
        float4 v1 = x4[(size_t)s1 * 16 + l];
        float4 v2 = x4[(size_t)s2 * 16 + l];
        float4 v3 = x4[(size_t)s3 * 16 + l];
        ax += (v0.x + v1.x) + (v2.x + v3.x);
        ay += (v0.y + v1.y) + (v2.y + v3.y);
        az += (v0.z + v1.z) + (v2.z + v3.z);
        aw += (v0.w + v1.w) + (v2.w + v3.w);
    }
    for (; p < e; ++p) {
        int s0 = colv[p];
        float4 v0 = x4[(size_t)s0 * 16 + l];
        ax += v0.x; ay += v0.y; az += v0.z; aw += v0.w;
    }
    float inv = 1.0f / fmaxf((float)(e - b), 1.0f);
    mh[(size_t)n * 16 + l] = make_ushort4(f2bf(ax * inv), f2bf(ay * inv),
                                          f2bf(az * inv), f2bf(aw * inv));
}

__global__ __launch_bounds__(256) void k_fused_legacy(
        const float* __restrict__ x,
        const float* __restrict__ Wl, const float* __restrict__ bl,
        const float* __restrict__ Wr,
        unsigned short* __restrict__ mh,   // in: bf16 mean; out: bf16 h
        float* __restrict__ pstats, int N) {
    __shared__ float sRed[4][128];
    const int tid = threadIdx.x;
    const int wid = tid >> 6;
    const int lane = tid & 63;
    const int l15 = lane & 15;
    const int quad = lane >> 4;

    short8 bfrag[4][4];
#pragma unroll
    for (int c = 0; c < 4; ++c) {
#pragma unroll
        for (int f = 0; f < 4; ++f) {
            const int n = f * 16 + l15;
            const float* wsrc = (c < 2)
                ? (Wl + (size_t)n * 64 + c * 32 + quad * 8)
                : (Wr + (size_t)n * 64 + (c - 2) * 32 + quad * 8);
            float4 w0 = *(const float4*)wsrc;
            float4 w1 = *(const float4*)(wsrc + 4);
            union { short8 v; unsigned short u[8]; } pk;
            pk.u[0] = f2bf(w0.x); pk.u[1] = f2bf(w0.y);
            pk.u[2] = f2bf(w0.z); pk.u[3] = f2bf(w0.w);
            pk.u[4] = f2bf(w1.x); pk.u[5] = f2bf(w1.y);
            pk.u[6] = f2bf(w1.z); pk.u[7] = f2bf(w1.w);
            bfrag[c][f] = pk.v;
        }
    }
    float blv[4];
#pragma unroll
    for (int f = 0; f < 4; ++f) blv[f] = bl[f * 16 + l15];

    const int tbase = blockIdx.x * 64 + wid * 16;
    const int mrow = tbase + l15;
    const int mld = (mrow < N) ? mrow : (N - 1);
    f32x4 acc[4] = {{0.f, 0.f, 0.f, 0.f}, {0.f, 0.f, 0.f, 0.f},
                    {0.f, 0.f, 0.f, 0.f}, {0.f, 0.f, 0.f, 0.f}};
#pragma unroll
    for (int c = 0; c < 2; ++c) {
        short8 a = *(const short8*)(mh + (size_t)mld * 64 + c * 32 + quad * 8);
#pragma unroll
        for (int f = 0; f < 4; ++f)
            acc[f] = __builtin_amdgcn_mfma_f32_16x16x32_bf16(a, bfrag[c][f], acc[f], 0, 0, 0);
    }
#pragma unroll
    for (int c = 0; c < 2; ++c) {
        const float* xp = x + (size_t)mld * 64 + c * 32 + quad * 8;
        float4 a0 = *(const float4*)xp;
        float4 a1 = *(const float4*)(xp + 4);
        union { short8 v; unsigned short u[8]; } pk;
        pk.u[0] = f2bf(a0.x); pk.u[1] = f2bf(a0.y);
        pk.u[2] = f2bf(a0.z); pk.u[3] = f2bf(a0.w);
        pk.u[4] = f2bf(a1.x); pk.u[5] = f2bf(a1.y);
        pk.u[6] = f2bf(a1.z); pk.u[7] = f2bf(a1.w);
#pragma unroll
        for (int f = 0; f < 4; ++f)
            acc[f] = __builtin_amdgcn_mfma_f32_16x16x32_bf16(pk.v, bfrag[c + 2][f], acc[f], 0, 0, 0);
    }

    float psum[4] = {0.f, 0.f, 0.f, 0.f};
    float psq[4] = {0.f, 0.f, 0.f, 0.f};
#pragma unroll
    for (int reg = 0; reg < 4; ++reg) {
        const int node = tbase + quad * 4 + reg;
        float hv[4];
        float ss = 0.f;
#pragma unroll
        for (int f = 0; f < 4; ++f) {
            hv[f] = acc[f][reg] + blv[f];
            ss += hv[f] * hv[f];
        }
        ss += __shfl_xor(ss, 1);
        ss += __shfl_xor(ss, 2);
        ss += __shfl_xor(ss, 4);
        ss += __shfl_xor(ss, 8);
        float sc = 1.0f / fmaxf(sqrtf(ss), 1e-12f);
        if (node < N) {
#pragma unroll
            for (int f = 0; f < 4; ++f) {
                float r = fmaxf(hv[f] * sc, 0.f);
                unsigned short rb = f2bf(r);
                float e = bf2f(rb);
                mh[(size_t)node * 64 + f * 16 + l15] = rb;
                psum[f] += e;
                psq[f] += e * e;
            }
        }
    }
#pragma unroll
    for (int f = 0; f < 4; ++f) {
        psum[f] += __shfl_xor(psum[f], 16);
        psum[f] += __shfl_xor(psum[f], 32);
        psq[f] += __shfl_xor(psq[f], 16);
        psq[f] += __shfl_xor(psq[f], 32);
    }
    if (lane < 16) {
#pragma unroll
        for (int f = 0; f < 4; ++f) {
            sRed[wid][f * 16 + l15] = psum[f];
            sRed[wid][64 + f * 16 + l15] = psq[f];
        }
    }
    __syncthreads();
    if (tid < 128) {
        float v = sRed[0][tid] + sRed[1][tid] + sRed[2][tid] + sRed[3][tid];
        pstats[(size_t)blockIdx.x * 128 + tid] = v;
    }
}

// ---------------------------------------------- reduce per-block BN partials
__global__ __launch_bounds__(64) void k_stats(const float* __restrict__ pstats,
                                              float* __restrict__ stats, int nblk) {
    int col = blockIdx.x;
    int l = threadIdx.x;
    float s = 0.f;
    for (int r = l; r < nblk; r += 64) s += pstats[(size_t)r * 128 + col];
    s += __shfl_xor(s, 1);
    s += __shfl_xor(s, 2);
    s += __shfl_xor(s, 4);
    s += __shfl_xor(s, 8);
    s += __shfl_xor(s, 16);
    s += __shfl_xor(s, 32);
    if (l == 0) stats[col] = s;
}

// ---------------------------------------------------------------- BN-fold + FC
__global__ __launch_bounds__(256) void k_out(
        const unsigned short* __restrict__ h, const float* __restrict__ stats,
        const float* __restrict__ gamma, const float* __restrict__ beta,
        const float* __restrict__ Wfc, const float* __restrict__ bfc,
        float* __restrict__ out, int N) {
    __shared__ float sWm[64 * 16];
    __shared__ float sShift[64];
    __shared__ float sBase[16];
    const int tid = threadIdx.x;
    const float invN = 1.0f / (float)N;
    if (tid < 64) {
        float mu = stats[tid] * invN;
        float var = stats[64 + tid] * invN - mu * mu;
        float sc = gamma[tid] / sqrtf(var + 1e-5f);
        sShift[tid] = beta[tid] - mu * sc;
#pragma unroll
        for (int c = 0; c < 16; ++c) sWm[tid * 16 + c] = Wfc[c * 64 + tid] * sc;
    }
    __syncthreads();
    if (tid < 16) {
        float b = bfc[tid];
#pragma unroll
        for (int j = 0; j < 64; ++j) b += sShift[j] * Wfc[tid * 64 + j];
        sBase[tid] = b;
    }
    __syncthreads();
    int g = blockIdx.x * 256 + tid;
    int n = g >> 4;
    int c = g & 15;
    if (n >= N) return;
    const ushort4* h4 = (const ushort4*)(h + (size_t)n * 64);
    float acc = sBase[c];
#pragma unroll
    for (int jq = 0; jq < 16; ++jq) {
        ushort4 v = h4[jq];
        acc += bf2f(v.x) * sWm[(jq * 4 + 0) * 16 + c];
        acc += bf2f(v.y) * sWm[(jq * 4 + 1) * 16 + c];
        acc += bf2f(v.z) * sWm[(jq * 4 + 2) * 16 + c];
        acc += bf2f(v.w) * sWm[(jq * 4 + 3) * 16 + c];
    }
    out[(size_t)n * 16 + c] = acc;
}

// ============================== host ==============================
extern "C" void kernel_launch(void* const* d_in, const int* in_sizes, int n_in,
                              void* d_out, int out_size, void* d_ws, size_t ws_size,
                              hipStream_t stream) {
    const int* eidx = (const int*)d_in[0];
    const float* x = (const float*)d_in[1];
    const float* Wl = (const float*)d_in[2];
    const float* bl = (const float*)d_in[3];
    const float* Wr = (const float*)d_in[4];
    const float* gamma = (const float*)d_in[5];
    const float* beta = (const float*)d_in[6];
    const float* Wfc = (const float*)d_in[7];
    const float* bfc = (const float*)d_in[8];
    float* out = (float*)d_out;

    const int E = in_sizes[0] / 2;
    const int N = in_sizes[1] / 64;
    const int NB = (N + 511) >> 9;               // <=256 for N<=131072
    const int NBLK = (E + CHUNK - 1) / CHUNK;    // <=256 for E<=2.09M
    const int fb = (N + 63) / 64;                // fused blocks (64 nodes/blk)
    const int n4 = N * 16;

    // layout (4B words):
    int* cnt = (int*)d_ws;                                     // NB*NBLK
    int* btot = cnt + (size_t)NB * NBLK;                       // NB
    int* rowptr = btot + NB;                                   // N+1
    float* pstats = (float*)(rowptr + N + 1);                  // fb*128
    float* stats = pstats + (size_t)fb * 128;                  // 128
    int* colv = (int*)(stats + 128);                           // E
    unsigned int* ebuf = (unsigned int*)(colv + E);            // E
    unsigned short* mh = (unsigned short*)(((uintptr_t)(ebuf + E) + 15) & ~(uintptr_t)15);
    unsigned short* xbf = mh + (size_t)N * 64;                 // N*64 bf16 opt

    size_t need_bf = (size_t)((char*)(xbf + (size_t)N * 64) - (char*)d_ws);
    const int use_bf = (ws_size >= need_bf) ? 1 : 0;

    int cbl = use_bf ? (n4 + 255) / 256 : 0;
    k_prep<<<NBLK + cbl, 256, 0, stream>>>(eidx, cnt, (const float4*)x,
                                           (ushort4*)xbf, E, NB, NBLK, n4, use_bf);
    k_scanbkt<<<NB, 256, 0, stream>>>(cnt, btot, NBLK);
    k_bscatter<<<NBLK, 256, 0, stream>>>(eidx, cnt, btot, ebuf, E, NB, NBLK);
    k_bfinal<<<NB, 256, 0, stream>>>(ebuf, btot, rowptr, colv, N, NB, E);

    if (use_bf) {
        // merged gather + MFMA + epilogue (no mh mean round-trip)
        k_gfused<<<fb, 256, 0, stream>>>(xbf, rowptr, colv, Wl, bl, Wr,
                                         mh, pstats, N);
    } else {
        int gblocks = (int)(((size_t)N * 16 + 255) / 256);
        k_gather_f32<<<gblocks, 256, 0, stream>>>((const float4*)x, rowptr, colv,
                                                  (ushort4*)mh, N);
        k_fused_legacy<<<fb, 256, 0, stream>>>(x, Wl, bl, Wr, mh, pstats, N);
    }

    k_stats<<<128, 64, 0, stream>>>(pstats, stats, fb);

    int oblocks = (int)(((size_t)N * 16 + 255) / 256);
    k_out<<<oblocks, 256, 0, stream>>>(mh, stats, gamma, beta, Wfc, bfc, out, N);
}